// Round 1
// baseline (4581.234 us; speedup 1.0000x reference)
//
#include <hip/hip_runtime.h>
#include <hip/hip_bf16.h>

#define DEV __device__ __forceinline__

typedef __bf16 bf16x8 __attribute__((ext_vector_type(8)));
typedef float  f32x4  __attribute__((ext_vector_type(4)));

// ---------------------------------------------------------------------------
// GEMM: Y[M][ldy] = X[M][K] * W[N][K]^T + bias[N], optional ReLU.
// M = 4096 fixed via grid.y = 32 (BM=128). N via grid.x (BN=128). BK=32.
// bf16 MFMA 16x16x32, fp32 accumulate; fp32 -> bf16 conversion during staging.
// ---------------------------------------------------------------------------
DEV bf16x8 cvt8(const float4 a, const float4 b) {
    bf16x8 r;
    r[0] = (__bf16)a.x; r[1] = (__bf16)a.y; r[2] = (__bf16)a.z; r[3] = (__bf16)a.w;
    r[4] = (__bf16)b.x; r[5] = (__bf16)b.y; r[6] = (__bf16)b.z; r[7] = (__bf16)b.w;
    return r;
}

template <int RELU>
__global__ __launch_bounds__(256) void gemm_bt(const float* __restrict__ X,
                                               const float* __restrict__ W,
                                               const float* __restrict__ bias,
                                               float* __restrict__ Y,
                                               int ldy, int K) {
    // LDS: 128 rows x 32 k, padded to 40 bf16 per row (80B stride: 2-way bank alias only)
    __shared__ __bf16 As[128 * 40];
    __shared__ __bf16 Bs[128 * 40];

    const int tid  = threadIdx.x;
    const int lane = tid & 63;
    const int wave = tid >> 6;
    const int wr   = wave >> 1, wc = wave & 1;     // 2x2 wave grid, 64x64 per wave
    const int lr   = lane & 15;
    const int lk   = (lane >> 4) << 3;             // k offset 0/8/16/24

    const int srow  = tid >> 1;                    // staging row 0..127
    const int shalf = (tid & 1) << 4;              // staging k offset 0/16

    const int mBase = blockIdx.y * 128;
    const int nBase = blockIdx.x * 128;

    const float* Xp = X + (size_t)(mBase + srow) * K + shalf;
    const float* Wp = W + (size_t)(nBase + srow) * K + shalf;

    f32x4 acc[4][4];
#pragma unroll
    for (int i = 0; i < 4; ++i)
#pragma unroll
        for (int j = 0; j < 4; ++j) {
            f32x4 z = {0.f, 0.f, 0.f, 0.f};
            acc[i][j] = z;
        }

    for (int kt = 0; kt < K; kt += 32) {
        float4 a0 = *(const float4*)(Xp + kt);
        float4 a1 = *(const float4*)(Xp + kt + 4);
        float4 a2 = *(const float4*)(Xp + kt + 8);
        float4 a3 = *(const float4*)(Xp + kt + 12);
        float4 b0 = *(const float4*)(Wp + kt);
        float4 b1 = *(const float4*)(Wp + kt + 4);
        float4 b2 = *(const float4*)(Wp + kt + 8);
        float4 b3 = *(const float4*)(Wp + kt + 12);

        *(bf16x8*)&As[srow * 40 + shalf]     = cvt8(a0, a1);
        *(bf16x8*)&As[srow * 40 + shalf + 8] = cvt8(a2, a3);
        *(bf16x8*)&Bs[srow * 40 + shalf]     = cvt8(b0, b1);
        *(bf16x8*)&Bs[srow * 40 + shalf + 8] = cvt8(b2, b3);

        __syncthreads();

        bf16x8 af[4], bfv[4];
#pragma unroll
        for (int i = 0; i < 4; ++i)
            af[i] = *(const bf16x8*)&As[(wr * 64 + i * 16 + lr) * 40 + lk];
#pragma unroll
        for (int j = 0; j < 4; ++j)
            bfv[j] = *(const bf16x8*)&Bs[(wc * 64 + j * 16 + lr) * 40 + lk];

#pragma unroll
        for (int i = 0; i < 4; ++i)
#pragma unroll
            for (int j = 0; j < 4; ++j)
                acc[i][j] = __builtin_amdgcn_mfma_f32_16x16x32_bf16(af[i], bfv[j], acc[i][j], 0, 0, 0);

        __syncthreads();
    }

    // Epilogue: C/D layout col = lane&15, row = (lane>>4)*4 + reg
    const int rsub = (lane >> 4) << 2;
#pragma unroll
    for (int i = 0; i < 4; ++i) {
#pragma unroll
        for (int j = 0; j < 4; ++j) {
            const int col = nBase + wc * 64 + j * 16 + lr;
            const float bv = bias[col];
#pragma unroll
            for (int rr = 0; rr < 4; ++rr) {
                const int row = mBase + wr * 64 + i * 16 + rsub + rr;
                float v = acc[i][j][rr] + bv;
                if (RELU) v = fmaxf(v, 0.f);
                Y[(size_t)row * ldy + col] = v;
            }
        }
    }
}

// ---------------------------------------------------------------------------
// Attention: one block per (b,h). 256 threads; thread t owns q-row t.
// QKV rows have stride 2304 (packed q|k|v). Online softmax, fp32.
// ---------------------------------------------------------------------------
__global__ __launch_bounds__(256) void attn_kernel(const float* __restrict__ Qb,
                                                   const float* __restrict__ Kb,
                                                   const float* __restrict__ Vb,
                                                   float* __restrict__ O,
                                                   int causal) {
    const int bh = blockIdx.x;
    const int b = bh / 12, h = bh - b * 12;
    const int tid = threadIdx.x;

    __shared__ float Ks[64][68];
    __shared__ float Vs[64][68];

    const float* qp = Qb + (size_t)(b * 256 + tid) * 2304 + h * 64;
    float4 q4[16];
#pragma unroll
    for (int i = 0; i < 16; ++i) q4[i] = *(const float4*)(qp + i * 4);

    float4 a4[16];
#pragma unroll
    for (int i = 0; i < 16; ++i) { a4[i].x = 0.f; a4[i].y = 0.f; a4[i].z = 0.f; a4[i].w = 0.f; }
    float mx = -1e30f, l = 0.f;

    const int srow = tid >> 2, spart = (tid & 3) * 16;

    for (int jt = 0; jt < 4; ++jt) {
        __syncthreads();   // previous tile's reads done
        const float* kp = Kb + (size_t)(b * 256 + jt * 64 + srow) * 2304 + h * 64 + spart;
        const float* vp = Vb + (size_t)(b * 256 + jt * 64 + srow) * 2304 + h * 64 + spart;
#pragma unroll
        for (int i = 0; i < 4; ++i) {
            *(float4*)&Ks[srow][spart + i * 4] = *(const float4*)(kp + i * 4);
            *(float4*)&Vs[srow][spart + i * 4] = *(const float4*)(vp + i * 4);
        }
        __syncthreads();

        int lim = causal ? (tid - jt * 64 + 1) : 64;
        if (lim > 64) lim = 64;
        for (int jj = 0; jj < lim; ++jj) {
            float s = 0.f;
#pragma unroll
            for (int i = 0; i < 16; ++i) {
                float4 kv = *(const float4*)&Ks[jj][i * 4];
                s += q4[i].x * kv.x + q4[i].y * kv.y + q4[i].z * kv.z + q4[i].w * kv.w;
            }
            s *= 0.125f;   // 1/sqrt(64)
            if (s > mx) {
                float sc = __expf(mx - s);
                l *= sc;
#pragma unroll
                for (int i = 0; i < 16; ++i) {
                    a4[i].x *= sc; a4[i].y *= sc; a4[i].z *= sc; a4[i].w *= sc;
                }
                mx = s;
            }
            float p = __expf(s - mx);
            l += p;
#pragma unroll
            for (int i = 0; i < 16; ++i) {
                float4 vv = *(const float4*)&Vs[jj][i * 4];
                a4[i].x += p * vv.x; a4[i].y += p * vv.y; a4[i].z += p * vv.z; a4[i].w += p * vv.w;
            }
        }
    }

    const float inv = 1.f / l;
    float* op = O + (size_t)(b * 256 + tid) * 768 + h * 64;
#pragma unroll
    for (int i = 0; i < 16; ++i) {
        float4 r;
        r.x = a4[i].x * inv; r.y = a4[i].y * inv; r.z = a4[i].z * inv; r.w = a4[i].w * inv;
        *(float4*)(op + i * 4) = r;
    }
}

// ---------------------------------------------------------------------------
// Fused residual + LayerNorm: x = LN(x + r) * g + b, row length 768.
// ---------------------------------------------------------------------------
__global__ __launch_bounds__(256) void resid_ln(float* __restrict__ x,
                                                const float* __restrict__ r,
                                                const float* __restrict__ g,
                                                const float* __restrict__ b) {
    const int row = blockIdx.x, tid = threadIdx.x;
    float* xp = x + (size_t)row * 768;
    const float* rp = r + (size_t)row * 768;

    float v0 = xp[tid] + rp[tid];
    float v1 = xp[tid + 256] + rp[tid + 256];
    float v2 = xp[tid + 512] + rp[tid + 512];

    __shared__ float red[4];
    float s = v0 + v1 + v2;
#pragma unroll
    for (int off = 32; off > 0; off >>= 1) s += __shfl_down(s, off, 64);
    if ((tid & 63) == 0) red[tid >> 6] = s;
    __syncthreads();
    const float mean = (red[0] + red[1] + red[2] + red[3]) * (1.0f / 768.0f);
    __syncthreads();

    float d0 = v0 - mean, d1 = v1 - mean, d2 = v2 - mean;
    float q = d0 * d0 + d1 * d1 + d2 * d2;
#pragma unroll
    for (int off = 32; off > 0; off >>= 1) q += __shfl_down(q, off, 64);
    if ((tid & 63) == 0) red[tid >> 6] = q;
    __syncthreads();
    const float inv = rsqrtf((red[0] + red[1] + red[2] + red[3]) * (1.0f / 768.0f) + 1e-5f);

    xp[tid]       = d0 * inv * g[tid]       + b[tid];
    xp[tid + 256] = d1 * inv * g[tid + 256] + b[tid + 256];
    xp[tid + 512] = d2 * inv * g[tid + 512] + b[tid + 512];
}

// ---------------------------------------------------------------------------
// x = encoded + sinusoidal PE
// ---------------------------------------------------------------------------
__global__ __launch_bounds__(256) void add_pe(const float* __restrict__ e, float* __restrict__ x) {
    const int i = blockIdx.x * 256 + threadIdx.x;
    const int m = i / 768;
    const int d = i - m * 768;
    const int s = m & 255;
    const int pair = d >> 1;
    // div = exp((2*pair) * (-ln(10000)/768))
    const float div = __expf((float)(2 * pair) * (-0.011992630693328381f));
    const float ang = (float)s * div;
    const float pe = (d & 1) ? cosf(ang) : sinf(ang);
    x[i] = e[i] + pe;
}

// ---------------------------------------------------------------------------
// proj[b][s][j] -> out[b][c=j%3][h=s][w=j/3]   (reshape + transpose)
// ---------------------------------------------------------------------------
__global__ __launch_bounds__(256) void write_out(const float* __restrict__ p, float* __restrict__ o) {
    const int i = blockIdx.x * 256 + threadIdx.x;
    const int m = i / 768;
    const int j = i - m * 768;
    const int b = m >> 8, s = m & 255;
    const int w = j / 3;
    const int c = j - w * 3;
    o[(size_t)b * 196608 + (size_t)c * 65536 + s * 256 + w] = p[i];
}

// ---------------------------------------------------------------------------
extern "C" void kernel_launch(void* const* d_in, const int* in_sizes, int n_in,
                              void* d_out, int out_size, void* d_ws, size_t ws_size,
                              hipStream_t stream) {
    const float* enc         = (const float*)d_in[0];
    const float* W_self_in   = (const float*)d_in[1];
    const float* b_self_in   = (const float*)d_in[2];
    const float* W_self_out  = (const float*)d_in[3];
    const float* b_self_out  = (const float*)d_in[4];
    const float* W_cross_in  = (const float*)d_in[5];
    const float* b_cross_in  = (const float*)d_in[6];
    const float* W_cross_out = (const float*)d_in[7];
    const float* b_cross_out = (const float*)d_in[8];
    const float* ln1_g       = (const float*)d_in[9];
    const float* ln1_b       = (const float*)d_in[10];
    const float* ln2_g       = (const float*)d_in[11];
    const float* ln2_b       = (const float*)d_in[12];
    const float* ln3_g       = (const float*)d_in[13];
    const float* ln3_b       = (const float*)d_in[14];
    const float* W_ff1       = (const float*)d_in[15];
    const float* b_ff1       = (const float*)d_in[16];
    const float* W_ff2       = (const float*)d_in[17];
    const float* b_ff2       = (const float*)d_in[18];
    const float* W_patch     = (const float*)d_in[19];
    const float* b_patch     = (const float*)d_in[20];

    float* out = (float*)d_out;
    float* ws  = (float*)d_ws;

    float* x      = ws;                       // 4096*768
    float* qkv    = ws + 3145728;             // 4096*2304 (also FFN buffer 4096*2048)
    float* attn_o = qkv + 9437184;            // 4096*768
    float* proj   = attn_o + 3145728;         // 4096*768

    add_pe<<<12288, 256, 0, stream>>>(enc, x);

    for (int l = 0; l < 6; ++l) {
        const float* Wsi = W_self_in  + (size_t)l * 2304 * 768;
        const float* Wso = W_self_out + (size_t)l * 768 * 768;
        const float* Wci = W_cross_in + (size_t)l * 2304 * 768;
        const float* Wco = W_cross_out+ (size_t)l * 768 * 768;
        const float* Wf1 = W_ff1      + (size_t)l * 2048 * 768;
        const float* Wf2 = W_ff2      + (size_t)l * 768 * 2048;

        // ---- self attention ----
        gemm_bt<0><<<dim3(18, 32), 256, 0, stream>>>(x, Wsi, b_self_in + l * 2304, qkv, 2304, 768);
        attn_kernel<<<192, 256, 0, stream>>>(qkv, qkv + 768, qkv + 1536, attn_o, 1);
        gemm_bt<0><<<dim3(6, 32), 256, 0, stream>>>(attn_o, Wso, b_self_out + l * 768, proj, 768, 768);
        resid_ln<<<4096, 256, 0, stream>>>(x, proj, ln1_g + l * 768, ln1_b + l * 768);

        // ---- cross attention (q from x, kv from encoded_patches) ----
        gemm_bt<0><<<dim3(6, 32), 256, 0, stream>>>(x, Wci, b_cross_in + l * 2304, qkv, 2304, 768);
        gemm_bt<0><<<dim3(12, 32), 256, 0, stream>>>(enc, Wci + (size_t)768 * 768,
                                                     b_cross_in + l * 2304 + 768, qkv + 768, 2304, 768);
        attn_kernel<<<192, 256, 0, stream>>>(qkv, qkv + 768, qkv + 1536, attn_o, 0);
        gemm_bt<0><<<dim3(6, 32), 256, 0, stream>>>(attn_o, Wco, b_cross_out + l * 768, proj, 768, 768);
        resid_ln<<<4096, 256, 0, stream>>>(x, proj, ln2_g + l * 768, ln2_b + l * 768);

        // ---- FFN ----
        gemm_bt<1><<<dim3(16, 32), 256, 0, stream>>>(x, Wf1, b_ff1 + l * 2048, qkv, 2048, 768);
        gemm_bt<0><<<dim3(6, 32), 256, 0, stream>>>(qkv, Wf2, b_ff2 + l * 768, proj, 768, 2048);
        resid_ln<<<4096, 256, 0, stream>>>(x, proj, ln3_g + l * 768, ln3_b + l * 768);
    }

    // ---- final projection + layout transform ----
    gemm_bt<0><<<dim3(6, 32), 256, 0, stream>>>(x, W_patch, b_patch, proj, 768, 768);
    write_out<<<12288, 256, 0, stream>>>(proj, out);
}

// Round 2
// 2301.710 us; speedup vs baseline: 1.9904x; 1.9904x over previous
//
#include <hip/hip_runtime.h>
#include <hip/hip_bf16.h>

#define DEV __device__ __forceinline__

typedef __bf16 bf16x8 __attribute__((ext_vector_type(8)));
typedef float  f32x4  __attribute__((ext_vector_type(4)));

DEV bf16x8 cvt8(const float4 a, const float4 b) {
    bf16x8 r;
    r[0] = (__bf16)a.x; r[1] = (__bf16)a.y; r[2] = (__bf16)a.z; r[3] = (__bf16)a.w;
    r[4] = (__bf16)b.x; r[5] = (__bf16)b.y; r[6] = (__bf16)b.z; r[7] = (__bf16)b.w;
    return r;
}

DEV void gload_lds16(const __bf16* g, __bf16* l) {
    __builtin_amdgcn_global_load_lds(
        (const __attribute__((address_space(1))) void*)g,
        (__attribute__((address_space(3))) void*)l, 16, 0, 0);
}

// ---------------------------------------------------------------------------
// Weight convert: fp32 [N][K] -> bf16 [N][K] with per-64-col-chunk granule
// XOR swizzle baked in: out[n][cb + g*8 + e] = in[n][cb + ((g^(n&7))*8) + e].
// global_load_lds then writes linear LDS whose content is already swizzled.
// ---------------------------------------------------------------------------
__global__ __launch_bounds__(256) void wconv(const float* __restrict__ W,
                                             __bf16* __restrict__ Wb, int K) {
    const int gid = blockIdx.x * 256 + threadIdx.x;
    const int gpr = K >> 3;
    const int n = gid / gpr;
    const int gi = gid - n * gpr;
    const int cb = (gi >> 3) << 6;
    const int g = gi & 7;
    const float* src = W + (size_t)n * K + cb + ((g ^ (n & 7)) << 3);
    float4 a = *(const float4*)src;
    float4 b = *(const float4*)(src + 4);
    *(bf16x8*)&Wb[(size_t)n * K + cb + (g << 3)] = cvt8(a, b);
}

// Linear fp32 -> bf16 (for encoded_patches as GEMM A operand)
__global__ __launch_bounds__(256) void cvt_lin(const float* __restrict__ in,
                                               __bf16* __restrict__ out) {
    const int g = blockIdx.x * 256 + threadIdx.x;
    float4 a = *(const float4*)(in + g * 8);
    float4 b = *(const float4*)(in + g * 8 + 4);
    *(bf16x8*)&out[g * 8] = cvt8(a, b);
}

// ---------------------------------------------------------------------------
// GEMM: Y[M=4096][ldy] = Xb[M][K] * Wb[N][K]^T + bias. Tile 128 x BN, BK=64.
// A: linear bf16, reg-staged, XOR-swizzled ds_write_b128.
// B: pre-swizzled bf16, global_load_lds(16B) into linear LDS.
// Both read with addr = r*64 + ((q ^ (r&7))<<3)  (conflict-free b128).
// ---------------------------------------------------------------------------
template <int RELU, int OUT_BF16, int BN>
__global__ __launch_bounds__(256) void gemm_bt(const __bf16* __restrict__ Xb,
                                               const __bf16* __restrict__ Wb,
                                               const float* __restrict__ bias,
                                               float* __restrict__ Yf,
                                               __bf16* __restrict__ Yb,
                                               int ldy, int K) {
    __shared__ __bf16 As[128 * 64];
    __shared__ __bf16 Bs[BN * 64];

    const int tid = threadIdx.x;
    const int lane = tid & 63;
    const int wave = tid >> 6;
    constexpr int NI = (BN == 128) ? 4 : 2;                 // 16-row frags per wave
    const int wr = (BN == 128) ? (wave >> 1) : wave;
    const int wc = (BN == 128) ? (wave & 1) : 0;
    const int lr = lane & 15;

    const int mBase = blockIdx.y * 128;
    const int nBase = blockIdx.x * BN;

    const int ar = tid >> 3;                                 // 0..31
    const int ap = tid & 7;                                  // granule pos
    const __bf16* Ab = Xb + (size_t)mBase * K + ap * 8;

    const int brow = lane >> 3;
    const __bf16* Bb = Wb + (size_t)nBase * K + (lane & 7) * 8;

    f32x4 acc[NI][4];
#pragma unroll
    for (int i = 0; i < NI; ++i)
#pragma unroll
        for (int j = 0; j < 4; ++j) {
            f32x4 z = {0.f, 0.f, 0.f, 0.f};
            acc[i][j] = z;
        }

    for (int kt = 0; kt < K; kt += 64) {
#pragma unroll
        for (int i = 0; i < 4; ++i) {
            const int row = i * 32 + ar;
            bf16x8 v = *(const bf16x8*)(Ab + (size_t)row * K + kt);
            *(bf16x8*)&As[row * 64 + ((ap ^ (row & 7)) << 3)] = v;
        }
#pragma unroll
        for (int i = 0; i < BN / 32; ++i) {
            const int r0 = wave * (BN / 4) + i * 8;
            gload_lds16(Bb + (size_t)(r0 + brow) * K + kt, &Bs[r0 * 64]);
        }
        __syncthreads();
#pragma unroll
        for (int kk = 0; kk < 2; ++kk) {
            const int q = (lane >> 4) + kk * 4;
            bf16x8 af[NI], bfv[4];
#pragma unroll
            for (int i = 0; i < NI; ++i) {
                const int r = wr * (NI * 16) + i * 16 + lr;
                af[i] = *(const bf16x8*)&As[r * 64 + ((q ^ (r & 7)) << 3)];
            }
#pragma unroll
            for (int j = 0; j < 4; ++j) {
                const int r = wc * 64 + j * 16 + lr;
                bfv[j] = *(const bf16x8*)&Bs[r * 64 + ((q ^ (r & 7)) << 3)];
            }
#pragma unroll
            for (int i = 0; i < NI; ++i)
#pragma unroll
                for (int j = 0; j < 4; ++j)
                    acc[i][j] = __builtin_amdgcn_mfma_f32_16x16x32_bf16(af[i], bfv[j], acc[i][j], 0, 0, 0);
        }
        __syncthreads();
    }

    const int rsub = (lane >> 4) << 2;
#pragma unroll
    for (int i = 0; i < NI; ++i)
#pragma unroll
        for (int j = 0; j < 4; ++j) {
            const int col = nBase + wc * 64 + j * 16 + lr;
            const float bv = bias[col];
#pragma unroll
            for (int rr = 0; rr < 4; ++rr) {
                const int row = mBase + wr * (NI * 16) + i * 16 + rsub + rr;
                float v = acc[i][j][rr] + bv;
                if (RELU) v = fmaxf(v, 0.f);
                if (OUT_BF16) Yb[(size_t)row * ldy + col] = (__bf16)v;
                else          Yf[(size_t)row * ldy + col] = v;
            }
        }
}

// ---------------------------------------------------------------------------
// Attention split-K: grid (bh=192, split=4). Thread = q-row, 64 k per split.
// QKV bf16 packed [4096][2304]. Writes unnormalized bf16 partials + (m,l).
// ---------------------------------------------------------------------------
__global__ __launch_bounds__(256) void attn_part(const __bf16* __restrict__ QKV,
                                                 __bf16* __restrict__ pacc,
                                                 float* __restrict__ pml,
                                                 int causal) {
    const int bh = blockIdx.x;
    const int s = blockIdx.y;
    const int b = bh / 12, h = bh - b * 12;
    const int tid = threadIdx.x;

    __shared__ float Ks[64][68];
    __shared__ float Vs[64][68];

    // stage K/V rows s*64..s*64+63 (bf16 -> fp32)
    const int srow = tid >> 2, sp = (tid & 3) << 4;
    {
        const __bf16* kp = QKV + (size_t)((b << 8) + (s << 6) + srow) * 2304 + 768 + (h << 6) + sp;
        bf16x8 k0 = *(const bf16x8*)kp;
        bf16x8 k1 = *(const bf16x8*)(kp + 8);
        bf16x8 v0 = *(const bf16x8*)(kp + 768);
        bf16x8 v1 = *(const bf16x8*)(kp + 776);
#pragma unroll
        for (int e = 0; e < 8; ++e) {
            Ks[srow][sp + e] = (float)k0[e];
            Ks[srow][sp + 8 + e] = (float)k1[e];
            Vs[srow][sp + e] = (float)v0[e];
            Vs[srow][sp + 8 + e] = (float)v1[e];
        }
    }

    // load q row (bf16 -> fp32 regs)
    const __bf16* qp = QKV + (size_t)((b << 8) + tid) * 2304 + (h << 6);
    float4 q4[16];
#pragma unroll
    for (int i = 0; i < 8; ++i) {
        bf16x8 qv = *(const bf16x8*)(qp + i * 8);
        q4[2 * i]     = make_float4((float)qv[0], (float)qv[1], (float)qv[2], (float)qv[3]);
        q4[2 * i + 1] = make_float4((float)qv[4], (float)qv[5], (float)qv[6], (float)qv[7]);
    }

    __syncthreads();

    int lim = 64;
    if (causal) {
        lim = tid + 1 - (s << 6);
        lim = lim < 0 ? 0 : (lim > 64 ? 64 : lim);
    }

    float4 a4[16];
#pragma unroll
    for (int i = 0; i < 16; ++i) { a4[i].x = 0.f; a4[i].y = 0.f; a4[i].z = 0.f; a4[i].w = 0.f; }
    float mx = -1e30f, l = 0.f;

    for (int jj = 0; jj < lim; ++jj) {
        float sv = 0.f;
#pragma unroll
        for (int i = 0; i < 16; ++i) {
            float4 kv = *(const float4*)&Ks[jj][i * 4];
            sv += q4[i].x * kv.x + q4[i].y * kv.y + q4[i].z * kv.z + q4[i].w * kv.w;
        }
        sv *= 0.125f;
        if (sv > mx) {
            float sc = __expf(mx - sv);
            l *= sc;
#pragma unroll
            for (int i = 0; i < 16; ++i) {
                a4[i].x *= sc; a4[i].y *= sc; a4[i].z *= sc; a4[i].w *= sc;
            }
            mx = sv;
        }
        float p = __expf(sv - mx);
        l += p;
#pragma unroll
        for (int i = 0; i < 16; ++i) {
            float4 vv = *(const float4*)&Vs[jj][i * 4];
            a4[i].x += p * vv.x; a4[i].y += p * vv.y; a4[i].z += p * vv.z; a4[i].w += p * vv.w;
        }
    }

    const int rp = ((s * 192 + bh) << 8) + tid;
    __bf16* pp = pacc + (size_t)rp * 64;
#pragma unroll
    for (int g = 0; g < 8; ++g)
        *(bf16x8*)(pp + g * 8) = cvt8(a4[2 * g], a4[2 * g + 1]);
    float2 ml; ml.x = mx; ml.y = l;
    *(float2*)&pml[rp * 2] = ml;
}

// Merge 4 split partials -> bf16 linear output rows [4096][768] (head-packed)
__global__ __launch_bounds__(256) void attn_merge(const __bf16* __restrict__ pacc,
                                                  const float* __restrict__ pml,
                                                  __bf16* __restrict__ out) {
    const int t = threadIdx.x;
    const int row = blockIdx.x * 32 + (t >> 3);       // 0..49151
    const int g = t & 7;
    const int bh = row >> 8, r = row & 255;
    const int b = bh / 12, h = bh - b * 12;

    float m[4], li[4];
    int rp[4];
#pragma unroll
    for (int s = 0; s < 4; ++s) {
        rp[s] = ((s * 192 + bh) << 8) + r;
        float2 ml = *(const float2*)&pml[rp[s] * 2];
        m[s] = ml.x; li[s] = ml.y;
    }
    const float M = fmaxf(fmaxf(m[0], m[1]), fmaxf(m[2], m[3]));
    float o[8] = {0.f, 0.f, 0.f, 0.f, 0.f, 0.f, 0.f, 0.f};
    float L = 0.f;
#pragma unroll
    for (int s = 0; s < 4; ++s) {
        const float w = __expf(m[s] - M);
        L += w * li[s];
        bf16x8 av = *(const bf16x8*)&pacc[(size_t)rp[s] * 64 + g * 8];
#pragma unroll
        for (int e = 0; e < 8; ++e) o[e] += w * (float)av[e];
    }
    const float inv = 1.f / L;
    bf16x8 ov;
#pragma unroll
    for (int e = 0; e < 8; ++e) ov[e] = (__bf16)(o[e] * inv);
    *(bf16x8*)&out[(size_t)((b << 8) + r) * 768 + (h << 6) + (g << 3)] = ov;
}

// ---------------------------------------------------------------------------
// Fused residual + LayerNorm; writes fp32 x and bf16 xb.
// ---------------------------------------------------------------------------
__global__ __launch_bounds__(256) void resid_ln(float* __restrict__ x,
                                                __bf16* __restrict__ xb,
                                                const float* __restrict__ r,
                                                const float* __restrict__ g,
                                                const float* __restrict__ b) {
    const int row = blockIdx.x, tid = threadIdx.x;
    float* xp = x + (size_t)row * 768;
    __bf16* xbp = xb + (size_t)row * 768;
    const float* rp = r + (size_t)row * 768;

    float v0 = xp[tid] + rp[tid];
    float v1 = xp[tid + 256] + rp[tid + 256];
    float v2 = xp[tid + 512] + rp[tid + 512];

    __shared__ float red[4];
    float s = v0 + v1 + v2;
#pragma unroll
    for (int off = 32; off > 0; off >>= 1) s += __shfl_down(s, off, 64);
    if ((tid & 63) == 0) red[tid >> 6] = s;
    __syncthreads();
    const float mean = (red[0] + red[1] + red[2] + red[3]) * (1.0f / 768.0f);
    __syncthreads();

    float d0 = v0 - mean, d1 = v1 - mean, d2 = v2 - mean;
    float q = d0 * d0 + d1 * d1 + d2 * d2;
#pragma unroll
    for (int off = 32; off > 0; off >>= 1) q += __shfl_down(q, off, 64);
    if ((tid & 63) == 0) red[tid >> 6] = q;
    __syncthreads();
    const float inv = rsqrtf((red[0] + red[1] + red[2] + red[3]) * (1.0f / 768.0f) + 1e-5f);

    const float o0 = d0 * inv * g[tid] + b[tid];
    const float o1 = d1 * inv * g[tid + 256] + b[tid + 256];
    const float o2 = d2 * inv * g[tid + 512] + b[tid + 512];
    xp[tid] = o0;       xbp[tid] = (__bf16)o0;
    xp[tid + 256] = o1; xbp[tid + 256] = (__bf16)o1;
    xp[tid + 512] = o2; xbp[tid + 512] = (__bf16)o2;
}

// x = enc + PE (fp32 + bf16 copies)
__global__ __launch_bounds__(256) void add_pe(const float* __restrict__ e,
                                              float* __restrict__ x,
                                              __bf16* __restrict__ xb) {
    const int i = blockIdx.x * 256 + threadIdx.x;
    const int m = i / 768;
    const int d = i - m * 768;
    const int s = m & 255;
    const int pair = d >> 1;
    const float div = __expf((float)(2 * pair) * (-0.011992630693328381f));
    const float ang = (float)s * div;
    const float pe = (d & 1) ? cosf(ang) : sinf(ang);
    const float v = e[i] + pe;
    x[i] = v;
    xb[i] = (__bf16)v;
}

// proj[b][s][j] -> out[b][c=j%3][h=s][w=j/3]
__global__ __launch_bounds__(256) void write_out(const float* __restrict__ p, float* __restrict__ o) {
    const int i = blockIdx.x * 256 + threadIdx.x;
    const int m = i / 768;
    const int j = i - m * 768;
    const int b = m >> 8, s = m & 255;
    const int w = j / 3;
    const int c = j - w * 3;
    o[(size_t)b * 196608 + (size_t)c * 65536 + s * 256 + w] = p[i];
}

// ---------------------------------------------------------------------------
extern "C" void kernel_launch(void* const* d_in, const int* in_sizes, int n_in,
                              void* d_out, int out_size, void* d_ws, size_t ws_size,
                              hipStream_t stream) {
    const float* enc         = (const float*)d_in[0];
    const float* W_self_in   = (const float*)d_in[1];
    const float* b_self_in   = (const float*)d_in[2];
    const float* W_self_out  = (const float*)d_in[3];
    const float* b_self_out  = (const float*)d_in[4];
    const float* W_cross_in  = (const float*)d_in[5];
    const float* b_cross_in  = (const float*)d_in[6];
    const float* W_cross_out = (const float*)d_in[7];
    const float* b_cross_out = (const float*)d_in[8];
    const float* ln1_g       = (const float*)d_in[9];
    const float* ln1_b       = (const float*)d_in[10];
    const float* ln2_g       = (const float*)d_in[11];
    const float* ln2_b       = (const float*)d_in[12];
    const float* ln3_g       = (const float*)d_in[13];
    const float* ln3_b       = (const float*)d_in[14];
    const float* W_ff1       = (const float*)d_in[15];
    const float* b_ff1       = (const float*)d_in[16];
    const float* W_ff2       = (const float*)d_in[17];
    const float* b_ff2       = (const float*)d_in[18];
    const float* W_patch     = (const float*)d_in[19];
    const float* b_patch     = (const float*)d_in[20];

    float* out = (float*)d_out;
    float* ws  = (float*)d_ws;

    // workspace layout (float offsets); total 18,579,456 f = 74.3 MB
    float*  x    = ws;                                 // 3,145,728 f
    __bf16* xb   = (__bf16*)(ws + 3145728);            // 3,145,728 bf
    __bf16* qkvb = (__bf16*)(ws + 4718592);            // 9,437,184 bf (also merged / ffn buf)
    __bf16* pacc = (__bf16*)(ws + 9437184);            // 12,582,912 bf (aliases proj)
    float*  proj = ws + 9437184;                       // 3,145,728 f
    float*  pml  = ws + 15728640;                      // 393,216 f
    __bf16* encb = (__bf16*)(ws + 16121856);           // 3,145,728 bf
    __bf16* wbuf = (__bf16*)(ws + 17694720);           // 1,769,472 bf max

    add_pe<<<12288, 256, 0, stream>>>(enc, x, xb);
    cvt_lin<<<1536, 256, 0, stream>>>(enc, encb);

    for (int l = 0; l < 6; ++l) {
        const float* Wsi = W_self_in   + (size_t)l * 2304 * 768;
        const float* Wso = W_self_out  + (size_t)l * 768 * 768;
        const float* Wci = W_cross_in  + (size_t)l * 2304 * 768;
        const float* Wco = W_cross_out + (size_t)l * 768 * 768;
        const float* Wf1 = W_ff1       + (size_t)l * 2048 * 768;
        const float* Wf2 = W_ff2       + (size_t)l * 768 * 2048;

        // ---- self attention ----
        wconv<<<864, 256, 0, stream>>>(Wsi, wbuf, 768);
        gemm_bt<0, 1, 128><<<dim3(18, 32), 256, 0, stream>>>(xb, wbuf, b_self_in + l * 2304,
                                                             nullptr, qkvb, 2304, 768);
        attn_part<<<dim3(192, 4), 256, 0, stream>>>(qkvb, pacc, pml, 1);
        attn_merge<<<1536, 256, 0, stream>>>(pacc, pml, qkvb);
        wconv<<<288, 256, 0, stream>>>(Wso, wbuf, 768);
        gemm_bt<0, 0, 64><<<dim3(12, 32), 256, 0, stream>>>(qkvb, wbuf, b_self_out + l * 768,
                                                            proj, nullptr, 768, 768);
        resid_ln<<<4096, 256, 0, stream>>>(x, xb, proj, ln1_g + l * 768, ln1_b + l * 768);

        // ---- cross attention ----
        wconv<<<864, 256, 0, stream>>>(Wci, wbuf, 768);
        gemm_bt<0, 1, 64><<<dim3(12, 32), 256, 0, stream>>>(xb, wbuf, b_cross_in + l * 2304,
                                                            nullptr, qkvb, 2304, 768);
        gemm_bt<0, 1, 128><<<dim3(12, 32), 256, 0, stream>>>(encb, wbuf + (size_t)768 * 768,
                                                             b_cross_in + l * 2304 + 768,
                                                             nullptr, qkvb + 768, 2304, 768);
        attn_part<<<dim3(192, 4), 256, 0, stream>>>(qkvb, pacc, pml, 0);
        attn_merge<<<1536, 256, 0, stream>>>(pacc, pml, qkvb);
        wconv<<<288, 256, 0, stream>>>(Wco, wbuf, 768);
        gemm_bt<0, 0, 64><<<dim3(12, 32), 256, 0, stream>>>(qkvb, wbuf, b_cross_out + l * 768,
                                                            proj, nullptr, 768, 768);
        resid_ln<<<4096, 256, 0, stream>>>(x, xb, proj, ln2_g + l * 768, ln2_b + l * 768);

        // ---- FFN ----
        wconv<<<768, 256, 0, stream>>>(Wf1, wbuf, 768);
        gemm_bt<1, 1, 128><<<dim3(16, 32), 256, 0, stream>>>(xb, wbuf, b_ff1 + l * 2048,
                                                             nullptr, qkvb, 2048, 768);
        wconv<<<768, 256, 0, stream>>>(Wf2, wbuf, 2048);
        gemm_bt<0, 0, 64><<<dim3(12, 32), 256, 0, stream>>>(qkvb, wbuf, b_ff2 + l * 768,
                                                            proj, nullptr, 768, 2048);
        resid_ln<<<4096, 256, 0, stream>>>(x, xb, proj, ln3_g + l * 768, ln3_b + l * 768);
    }

    // ---- final projection + layout transform ----
    wconv<<<288, 256, 0, stream>>>(W_patch, wbuf, 768);
    gemm_bt<0, 0, 64><<<dim3(12, 32), 256, 0, stream>>>(xb, wbuf, b_patch,
                                                        proj, nullptr, 768, 768);
    write_out<<<12288, 256, 0, stream>>>(proj, out);
}

// Round 3
// 1486.354 us; speedup vs baseline: 3.0822x; 1.5486x over previous
//
#include <hip/hip_runtime.h>
#include <hip/hip_bf16.h>

#define DEV __device__ __forceinline__

typedef __bf16 bf16x8 __attribute__((ext_vector_type(8)));
typedef __bf16 bf16x4 __attribute__((ext_vector_type(4)));
typedef float  f32x4  __attribute__((ext_vector_type(4)));

DEV bf16x8 cvt8(const float4 a, const float4 b) {
    bf16x8 r;
    r[0] = (__bf16)a.x; r[1] = (__bf16)a.y; r[2] = (__bf16)a.z; r[3] = (__bf16)a.w;
    r[4] = (__bf16)b.x; r[5] = (__bf16)b.y; r[6] = (__bf16)b.z; r[7] = (__bf16)b.w;
    return r;
}

DEV void gload_lds16(const __bf16* g, __bf16* l) {
    __builtin_amdgcn_global_load_lds(
        (const __attribute__((address_space(1))) void*)g,
        (__attribute__((address_space(3))) void*)l, 16, 0, 0);
}

// ---------------------------------------------------------------------------
// Weight converts: fp32 [N][K] -> bf16 [N][K] with per-64-col granule XOR
// swizzle baked in (granule g of row n stores source granule g^(n&7)).
// ---------------------------------------------------------------------------
DEV void wconv_one(const float* __restrict__ src, __bf16* __restrict__ dst,
                   int lg, int gpr, int K) {
    const int n = lg / gpr;
    const int gi = lg - n * gpr;
    const int cb = (gi >> 3) << 6;
    const int g = gi & 7;
    const float* sp = src + (size_t)n * K + cb + ((g ^ (n & 7)) << 3);
    float4 a = *(const float4*)sp;
    float4 b = *(const float4*)(sp + 4);
    *(bf16x8*)&dst[(size_t)lg * 8] = cvt8(a, b);
}

// single matrix, K=768 (W_patch)
__global__ __launch_bounds__(256) void wconv(const float* __restrict__ W,
                                             __bf16* __restrict__ Wb) {
    const int gid = blockIdx.x * 256 + threadIdx.x;
    wconv_one(W, Wb, gid, 96, 768);
}

// 4 attention matrices of one layer (all K=768): self_in, self_out, cross_in, cross_out
__global__ __launch_bounds__(256) void wconv4(const float* __restrict__ s0,
                                              const float* __restrict__ s1,
                                              const float* __restrict__ s2,
                                              const float* __restrict__ s3,
                                              __bf16* __restrict__ dst) {
    const int gid = blockIdx.x * 256 + threadIdx.x;   // < 589824 granules
    if (gid < 221184)      wconv_one(s0, dst,           gid,          96, 768);
    else if (gid < 294912) wconv_one(s1, dst + 1769472, gid - 221184, 96, 768);
    else if (gid < 516096) wconv_one(s2, dst + 2359296, gid - 294912, 96, 768);
    else                   wconv_one(s3, dst + 4128768, gid - 516096, 96, 768);
}

// ff1 (2048x768) + ff2 (768x2048)
__global__ __launch_bounds__(256) void wconv_ff(const float* __restrict__ f1,
                                                const float* __restrict__ f2,
                                                __bf16* __restrict__ dst) {
    const int gid = blockIdx.x * 256 + threadIdx.x;   // < 393216
    if (gid < 196608) wconv_one(f1, dst,           gid,          96, 768);
    else              wconv_one(f2, dst + 1572864, gid - 196608, 256, 2048);
}

// Linear fp32 -> bf16 (encoded_patches as GEMM A operand)
__global__ __launch_bounds__(256) void cvt_lin(const float* __restrict__ in,
                                               __bf16* __restrict__ out) {
    const int g = blockIdx.x * 256 + threadIdx.x;
    float4 a = *(const float4*)(in + g * 8);
    float4 b = *(const float4*)(in + g * 8 + 4);
    *(bf16x8*)&out[g * 8] = cvt8(a, b);
}

// ---------------------------------------------------------------------------
// GEMM: Y[M=4096][ldy] = Xb[M][K] * Wb[N][K]^T + bias. Tile 128 x BN, BK=64.
// ---------------------------------------------------------------------------
template <int RELU, int OUT_BF16, int BN>
__global__ __launch_bounds__(256) void gemm_bt(const __bf16* __restrict__ Xb,
                                               const __bf16* __restrict__ Wb,
                                               const float* __restrict__ bias,
                                               float* __restrict__ Yf,
                                               __bf16* __restrict__ Yb,
                                               int ldy, int K) {
    __shared__ __bf16 As[128 * 64];
    __shared__ __bf16 Bs[BN * 64];

    const int tid = threadIdx.x;
    const int lane = tid & 63;
    const int wave = tid >> 6;
    constexpr int NI = (BN == 128) ? 4 : 2;
    const int wr = (BN == 128) ? (wave >> 1) : wave;
    const int wc = (BN == 128) ? (wave & 1) : 0;
    const int lr = lane & 15;

    const int mBase = blockIdx.y * 128;
    const int nBase = blockIdx.x * BN;

    const int ar = tid >> 3;
    const int ap = tid & 7;
    const __bf16* Ab = Xb + (size_t)mBase * K + ap * 8;

    const int brow = lane >> 3;
    const __bf16* Bb = Wb + (size_t)nBase * K + (lane & 7) * 8;

    f32x4 acc[NI][4];
#pragma unroll
    for (int i = 0; i < NI; ++i)
#pragma unroll
        for (int j = 0; j < 4; ++j) {
            f32x4 z = {0.f, 0.f, 0.f, 0.f};
            acc[i][j] = z;
        }

    for (int kt = 0; kt < K; kt += 64) {
#pragma unroll
        for (int i = 0; i < 4; ++i) {
            const int row = i * 32 + ar;
            bf16x8 v = *(const bf16x8*)(Ab + (size_t)row * K + kt);
            *(bf16x8*)&As[row * 64 + ((ap ^ (row & 7)) << 3)] = v;
        }
#pragma unroll
        for (int i = 0; i < BN / 32; ++i) {
            const int r0 = wave * (BN / 4) + i * 8;
            gload_lds16(Bb + (size_t)(r0 + brow) * K + kt, &Bs[r0 * 64]);
        }
        __syncthreads();
#pragma unroll
        for (int kk = 0; kk < 2; ++kk) {
            const int q = (lane >> 4) + kk * 4;
            bf16x8 af[NI], bfv[4];
#pragma unroll
            for (int i = 0; i < NI; ++i) {
                const int r = wr * (NI * 16) + i * 16 + lr;
                af[i] = *(const bf16x8*)&As[r * 64 + ((q ^ (r & 7)) << 3)];
            }
#pragma unroll
            for (int j = 0; j < 4; ++j) {
                const int r = wc * 64 + j * 16 + lr;
                bfv[j] = *(const bf16x8*)&Bs[r * 64 + ((q ^ (r & 7)) << 3)];
            }
#pragma unroll
            for (int i = 0; i < NI; ++i)
#pragma unroll
                for (int j = 0; j < 4; ++j)
                    acc[i][j] = __builtin_amdgcn_mfma_f32_16x16x32_bf16(af[i], bfv[j], acc[i][j], 0, 0, 0);
        }
        __syncthreads();
    }

    const int rsub = (lane >> 4) << 2;
#pragma unroll
    for (int i = 0; i < NI; ++i)
#pragma unroll
        for (int j = 0; j < 4; ++j) {
            const int col = nBase + wc * 64 + j * 16 + lr;
            const float bv = bias[col];
#pragma unroll
            for (int rr = 0; rr < 4; ++rr) {
                const int row = mBase + wr * (NI * 16) + i * 16 + rsub + rr;
                float v = acc[i][j][rr] + bv;
                if (RELU) v = fmaxf(v, 0.f);
                if (OUT_BF16) Yb[(size_t)row * ldy + col] = (__bf16)v;
                else          Yf[(size_t)row * ldy + col] = v;
            }
        }
}

// ---------------------------------------------------------------------------
// MFMA flash attention. Grid (192 bh, 4 q-blocks of 64). 4 waves x 16 q rows.
// Swapped QK^T (S^T frags, col=q) -> lane-local softmax; P via swizzled LDS;
// PV with A = V^T (scalar transposed reads from stride-66 V tile), B = P.
// Output O[q][d] written as bf16 (head-packed rows of 768).
// ---------------------------------------------------------------------------
__global__ __launch_bounds__(256) void attn_mfma(const __bf16* __restrict__ QKV,
                                                 __bf16* __restrict__ Oout,
                                                 int causal) {
    const int bh = blockIdx.x;
    const int qq = blockIdx.y;
    const int b = bh / 12, h = bh - b * 12;
    const int tid = threadIdx.x;
    const int lane = tid & 63;
    const int w = tid >> 6;
    const int g = lane >> 4;
    const int c = lane & 15;
    const int c7 = c & 7;

    __shared__ __bf16 Ks[64 * 64];   // XOR-granule swizzled, rows k
    __shared__ __bf16 Vs[64 * 66];   // stride 66: conflict-free transposed reads
    __shared__ __bf16 Ps[64 * 64];   // XOR-granule swizzled, rows q (wave-private bands)

    const int q64 = (w << 4) + c;            // q within the 64-row block
    const int qrow = (qq << 6) + q64;        // q within sequence
    const __bf16* qp = QKV + (size_t)((b << 8) + qrow) * 2304 + (h << 6) + (g << 3);
    bf16x8 qf0 = *(const bf16x8*)qp;         // Q B-frag kd=0 (d = 8g..)
    bf16x8 qf1 = *(const bf16x8*)(qp + 32);  // kd=1 (d = 32+8g..)

    f32x4 oacc[4];
#pragma unroll
    for (int i = 0; i < 4; ++i) { f32x4 z = {0.f, 0.f, 0.f, 0.f}; oacc[i] = z; }
    float mrun = -1e30f, lrun = 0.f;

    const int nt = causal ? (qq + 1) : 4;
    const int sr = tid >> 2;                 // staging row 0..63
    const int sg0 = (tid & 3) << 1;          // staging granule base
    const int sp = sg0 << 3;                 // elem offset 0/16/32/48

    for (int kt = 0; kt < nt; ++kt) {
        __syncthreads();
        {
            const __bf16* kp = QKV + (size_t)((b << 8) + (kt << 6) + sr) * 2304 + 768 + (h << 6) + sp;
            bf16x8 k0 = *(const bf16x8*)kp;
            bf16x8 k1 = *(const bf16x8*)(kp + 8);
            bf16x8 v0 = *(const bf16x8*)(kp + 768);
            bf16x8 v1 = *(const bf16x8*)(kp + 776);
            const int s7 = sr & 7;
            *(bf16x8*)&Ks[(sr << 6) + ((sg0 ^ s7) << 3)] = k0;
            *(bf16x8*)&Ks[(sr << 6) + (((sg0 + 1) ^ s7) << 3)] = k1;
            // Vs row stride 66 (132B) -> only 4B-aligned; store as 8 dwords
            uint32_t* vd = (uint32_t*)&Vs[sr * 66 + sp];
            const uint32_t* u0 = (const uint32_t*)&v0;
            const uint32_t* u1 = (const uint32_t*)&v1;
            vd[0] = u0[0]; vd[1] = u0[1]; vd[2] = u0[2]; vd[3] = u0[3];
            vd[4] = u1[0]; vd[5] = u1[1]; vd[6] = u1[2]; vd[7] = u1[3];
        }
        __syncthreads();

        // ---- QK^T (swapped): S^T frags, rows k = 16mf+4g+r, col q ----
        f32x4 sc[4];
#pragma unroll
        for (int mf = 0; mf < 4; ++mf) { f32x4 z = {0.f, 0.f, 0.f, 0.f}; sc[mf] = z; }
#pragma unroll
        for (int mf = 0; mf < 4; ++mf) {
            const int row = (mf << 4) + c;
            bf16x8 af0 = *(const bf16x8*)&Ks[(row << 6) + ((g ^ c7) << 3)];
            sc[mf] = __builtin_amdgcn_mfma_f32_16x16x32_bf16(af0, qf0, sc[mf], 0, 0, 0);
            bf16x8 af1 = *(const bf16x8*)&Ks[(row << 6) + (((g + 4) ^ c7) << 3)];
            sc[mf] = __builtin_amdgcn_mfma_f32_16x16x32_bf16(af1, qf1, sc[mf], 0, 0, 0);
        }

        // ---- scale + causal mask + row-max ----
        const int diag = (causal && kt == qq);
        float tm = -1e30f;
#pragma unroll
        for (int mf = 0; mf < 4; ++mf)
#pragma unroll
            for (int r = 0; r < 4; ++r) {
                float v = sc[mf][r] * 0.125f;
                if (diag && ((mf << 4) + (g << 2) + r > q64)) v = -1e30f;
                sc[mf][r] = v;
                tm = fmaxf(tm, v);
            }
        tm = fmaxf(tm, __shfl_xor(tm, 16));
        tm = fmaxf(tm, __shfl_xor(tm, 32));
        const float mnew = fmaxf(mrun, tm);
        const float rs = __expf(mrun - mnew);
        mrun = mnew;
        lrun *= rs;
#pragma unroll
        for (int i = 0; i < 4; ++i) {
            oacc[i][0] *= rs; oacc[i][1] *= rs; oacc[i][2] *= rs; oacc[i][3] *= rs;
        }

        // ---- P = exp(S - m), lane-partial l, store to swizzled Ps ----
#pragma unroll
        for (int mf = 0; mf < 4; ++mf) {
            const int kg = (mf << 1) + (g >> 1);
            const int e = (g & 1) << 2;
#pragma unroll
            for (int r = 0; r < 4; ++r) {
                float p = __expf(sc[mf][r] - mnew);
                lrun += p;
                Ps[(q64 << 6) + ((kg ^ c7) << 3) + e + r] = (__bf16)p;
            }
        }

        // ---- PV: O^T[d][q] += V^T x P ----
#pragma unroll
        for (int kc = 0; kc < 2; ++kc) {
            bf16x8 pb = *(const bf16x8*)&Ps[(q64 << 6) + (((g + (kc << 2)) ^ c7) << 3)];
#pragma unroll
            for (int df = 0; df < 4; ++df) {
                bf16x8 av;
#pragma unroll
                for (int j = 0; j < 8; ++j)
                    av[j] = Vs[((g << 3) + j + (kc << 5)) * 66 + (df << 4) + c];
                oacc[df] = __builtin_amdgcn_mfma_f32_16x16x32_bf16(av, pb, oacc[df], 0, 0, 0);
            }
        }
    }

    // ---- epilogue ----
    lrun += __shfl_xor(lrun, 16);
    lrun += __shfl_xor(lrun, 32);
    const float inv = 1.f / lrun;
    __bf16* op = Oout + (size_t)((b << 8) + qrow) * 768 + (h << 6) + (g << 2);
#pragma unroll
    for (int df = 0; df < 4; ++df) {
        bf16x4 ov;
        ov[0] = (__bf16)(oacc[df][0] * inv);
        ov[1] = (__bf16)(oacc[df][1] * inv);
        ov[2] = (__bf16)(oacc[df][2] * inv);
        ov[3] = (__bf16)(oacc[df][3] * inv);
        *(bf16x4*)(op + (df << 4)) = ov;
    }
}

// ---------------------------------------------------------------------------
// Fused residual + LayerNorm; writes fp32 x and bf16 xb.
// ---------------------------------------------------------------------------
__global__ __launch_bounds__(256) void resid_ln(float* __restrict__ x,
                                                __bf16* __restrict__ xb,
                                                const float* __restrict__ r,
                                                const float* __restrict__ g,
                                                const float* __restrict__ b) {
    const int row = blockIdx.x, tid = threadIdx.x;
    float* xp = x + (size_t)row * 768;
    __bf16* xbp = xb + (size_t)row * 768;
    const float* rp = r + (size_t)row * 768;

    float v0 = xp[tid] + rp[tid];
    float v1 = xp[tid + 256] + rp[tid + 256];
    float v2 = xp[tid + 512] + rp[tid + 512];

    __shared__ float red[4];
    float s = v0 + v1 + v2;
#pragma unroll
    for (int off = 32; off > 0; off >>= 1) s += __shfl_down(s, off, 64);
    if ((tid & 63) == 0) red[tid >> 6] = s;
    __syncthreads();
    const float mean = (red[0] + red[1] + red[2] + red[3]) * (1.0f / 768.0f);
    __syncthreads();

    float d0 = v0 - mean, d1 = v1 - mean, d2 = v2 - mean;
    float q = d0 * d0 + d1 * d1 + d2 * d2;
#pragma unroll
    for (int off = 32; off > 0; off >>= 1) q += __shfl_down(q, off, 64);
    if ((tid & 63) == 0) red[tid >> 6] = q;
    __syncthreads();
    const float inv = rsqrtf((red[0] + red[1] + red[2] + red[3]) * (1.0f / 768.0f) + 1e-5f);

    const float o0 = d0 * inv * g[tid] + b[tid];
    const float o1 = d1 * inv * g[tid + 256] + b[tid + 256];
    const float o2 = d2 * inv * g[tid + 512] + b[tid + 512];
    xp[tid] = o0;       xbp[tid] = (__bf16)o0;
    xp[tid + 256] = o1; xbp[tid + 256] = (__bf16)o1;
    xp[tid + 512] = o2; xbp[tid + 512] = (__bf16)o2;
}

__global__ __launch_bounds__(256) void add_pe(const float* __restrict__ e,
                                              float* __restrict__ x,
                                              __bf16* __restrict__ xb) {
    const int i = blockIdx.x * 256 + threadIdx.x;
    const int m = i / 768;
    const int d = i - m * 768;
    const int s = m & 255;
    const int pair = d >> 1;
    const float div = __expf((float)(2 * pair) * (-0.011992630693328381f));
    const float ang = (float)s * div;
    const float pe = (d & 1) ? cosf(ang) : sinf(ang);
    const float v = e[i] + pe;
    x[i] = v;
    xb[i] = (__bf16)v;
}

__global__ __launch_bounds__(256) void write_out(const float* __restrict__ p, float* __restrict__ o) {
    const int i = blockIdx.x * 256 + threadIdx.x;
    const int m = i / 768;
    const int j = i - m * 768;
    const int b = m >> 8, s = m & 255;
    const int w = j / 3;
    const int c = j - w * 3;
    o[(size_t)b * 196608 + (size_t)c * 65536 + s * 256 + w] = p[i];
}

// ---------------------------------------------------------------------------
extern "C" void kernel_launch(void* const* d_in, const int* in_sizes, int n_in,
                              void* d_out, int out_size, void* d_ws, size_t ws_size,
                              hipStream_t stream) {
    const float* enc         = (const float*)d_in[0];
    const float* W_self_in   = (const float*)d_in[1];
    const float* b_self_in   = (const float*)d_in[2];
    const float* W_self_out  = (const float*)d_in[3];
    const float* b_self_out  = (const float*)d_in[4];
    const float* W_cross_in  = (const float*)d_in[5];
    const float* b_cross_in  = (const float*)d_in[6];
    const float* W_cross_out = (const float*)d_in[7];
    const float* b_cross_out = (const float*)d_in[8];
    const float* ln1_g       = (const float*)d_in[9];
    const float* ln1_b       = (const float*)d_in[10];
    const float* ln2_g       = (const float*)d_in[11];
    const float* ln2_b       = (const float*)d_in[12];
    const float* ln3_g       = (const float*)d_in[13];
    const float* ln3_b       = (const float*)d_in[14];
    const float* W_ff1       = (const float*)d_in[15];
    const float* b_ff1       = (const float*)d_in[16];
    const float* W_ff2       = (const float*)d_in[17];
    const float* b_ff2       = (const float*)d_in[18];
    const float* W_patch     = (const float*)d_in[19];
    const float* b_patch     = (const float*)d_in[20];

    float* out = (float*)d_out;
    float* ws  = (float*)d_ws;

    // workspace (float offsets), total 18,087,936 f = 72.4 MB
    float*  x       = ws;                                  // 3,145,728 f
    __bf16* xb      = (__bf16*)(ws + 3145728);             // 3,145,728 bf
    __bf16* qkvb    = (__bf16*)(ws + 4718592);             // 9,437,184 bf (also FFN buf)
    __bf16* attnout = (__bf16*)(ws + 9437184);             // 3,145,728 bf
    float*  proj    = ws + 11010048;                       // 3,145,728 f
    __bf16* encb    = (__bf16*)(ws + 14155776);            // 3,145,728 bf
    __bf16* wbuf    = (__bf16*)(ws + 15728640);            // 4,718,592 bf

    add_pe<<<12288, 256, 0, stream>>>(enc, x, xb);
    cvt_lin<<<1536, 256, 0, stream>>>(enc, encb);

    for (int l = 0; l < 6; ++l) {
        const float* Wsi = W_self_in   + (size_t)l * 2304 * 768;
        const float* Wso = W_self_out  + (size_t)l * 768 * 768;
        const float* Wci = W_cross_in  + (size_t)l * 2304 * 768;
        const float* Wco = W_cross_out + (size_t)l * 768 * 768;
        const float* Wf1 = W_ff1       + (size_t)l * 2048 * 768;
        const float* Wf2 = W_ff2       + (size_t)l * 768 * 2048;

        wconv4<<<2304, 256, 0, stream>>>(Wsi, Wso, Wci, Wco, wbuf);

        // ---- self attention ----
        gemm_bt<0, 1, 128><<<dim3(18, 32), 256, 0, stream>>>(xb, wbuf, b_self_in + l * 2304,
                                                             nullptr, qkvb, 2304, 768);
        attn_mfma<<<dim3(192, 4), 256, 0, stream>>>(qkvb, attnout, 1);
        gemm_bt<0, 0, 64><<<dim3(12, 32), 256, 0, stream>>>(attnout, wbuf + 1769472,
                                                            b_self_out + l * 768,
                                                            proj, nullptr, 768, 768);
        resid_ln<<<4096, 256, 0, stream>>>(x, xb, proj, ln1_g + l * 768, ln1_b + l * 768);

        // ---- cross attention ----
        gemm_bt<0, 1, 64><<<dim3(12, 32), 256, 0, stream>>>(xb, wbuf + 2359296,
                                                            b_cross_in + l * 2304,
                                                            nullptr, qkvb, 2304, 768);
        gemm_bt<0, 1, 128><<<dim3(12, 32), 256, 0, stream>>>(encb, wbuf + 2949120,
                                                             b_cross_in + l * 2304 + 768,
                                                             nullptr, qkvb + 768, 2304, 768);
        attn_mfma<<<dim3(192, 4), 256, 0, stream>>>(qkvb, attnout, 0);
        gemm_bt<0, 0, 64><<<dim3(12, 32), 256, 0, stream>>>(attnout, wbuf + 4128768,
                                                            b_cross_out + l * 768,
                                                            proj, nullptr, 768, 768);
        resid_ln<<<4096, 256, 0, stream>>>(x, xb, proj, ln2_g + l * 768, ln2_b + l * 768);

        // ---- FFN ----
        wconv_ff<<<1536, 256, 0, stream>>>(Wf1, Wf2, wbuf);
        gemm_bt<1, 1, 128><<<dim3(16, 32), 256, 0, stream>>>(xb, wbuf, b_ff1 + l * 2048,
                                                             nullptr, qkvb, 2048, 768);
        gemm_bt<0, 0, 64><<<dim3(12, 32), 256, 0, stream>>>(qkvb, wbuf + 1572864,
                                                            b_ff2 + l * 768,
                                                            proj, nullptr, 768, 2048);
        resid_ln<<<4096, 256, 0, stream>>>(x, xb, proj, ln3_g + l * 768, ln3_b + l * 768);
    }

    // ---- final projection + layout transform ----
    wconv<<<288, 256, 0, stream>>>(W_patch, wbuf);
    gemm_bt<0, 0, 64><<<dim3(12, 32), 256, 0, stream>>>(xb, wbuf, b_patch,
                                                        proj, nullptr, 768, 768);
    write_out<<<12288, 256, 0, stream>>>(proj, out);
}

// Round 4
// 1450.052 us; speedup vs baseline: 3.1594x; 1.0250x over previous
//
#include <hip/hip_runtime.h>
#include <hip/hip_bf16.h>

#define DEV __device__ __forceinline__

typedef __bf16 bf16x8 __attribute__((ext_vector_type(8)));
typedef __bf16 bf16x4 __attribute__((ext_vector_type(4)));
typedef float  f32x4  __attribute__((ext_vector_type(4)));

DEV bf16x8 cvt8(const float4 a, const float4 b) {
    bf16x8 r;
    r[0] = (__bf16)a.x; r[1] = (__bf16)a.y; r[2] = (__bf16)a.z; r[3] = (__bf16)a.w;
    r[4] = (__bf16)b.x; r[5] = (__bf16)b.y; r[6] = (__bf16)b.z; r[7] = (__bf16)b.w;
    return r;
}

DEV void gload_lds16(const __bf16* g, __bf16* l) {
    __builtin_amdgcn_global_load_lds(
        (const __attribute__((address_space(1))) void*)g,
        (__attribute__((address_space(3))) void*)l, 16, 0, 0);
}

// swizzled column for bf16 activation/weight buffers: within each 64-elem
// chunk, granule g stores source granule g^(row&7).
DEV int swzcol(int col, int row) {
    return (col & ~63) | ((((col >> 3) & 7) ^ (row & 7)) << 3) | (col & 7);
}

// ---------------------------------------------------------------------------
// Weight converts: fp32 [N][K] -> bf16 [N][K], granule-swizzled.
// ---------------------------------------------------------------------------
DEV void wconv_one(const float* __restrict__ src, __bf16* __restrict__ dst,
                   int lg, int gpr, int K) {
    const int n = lg / gpr;
    const int gi = lg - n * gpr;
    const int cb = (gi >> 3) << 6;
    const int g = gi & 7;
    const float* sp = src + (size_t)n * K + cb + ((g ^ (n & 7)) << 3);
    float4 a = *(const float4*)sp;
    float4 b = *(const float4*)(sp + 4);
    *(bf16x8*)&dst[(size_t)lg * 8] = cvt8(a, b);
}

__global__ __launch_bounds__(256) void wconv(const float* __restrict__ W,
                                             __bf16* __restrict__ Wb) {
    const int gid = blockIdx.x * 256 + threadIdx.x;
    wconv_one(W, Wb, gid, 96, 768);
}

__global__ __launch_bounds__(256) void wconv4(const float* __restrict__ s0,
                                              const float* __restrict__ s1,
                                              const float* __restrict__ s2,
                                              const float* __restrict__ s3,
                                              __bf16* __restrict__ dst) {
    const int gid = blockIdx.x * 256 + threadIdx.x;   // < 589824
    if (gid < 221184)      wconv_one(s0, dst,           gid,          96, 768);
    else if (gid < 294912) wconv_one(s1, dst + 1769472, gid - 221184, 96, 768);
    else if (gid < 516096) wconv_one(s2, dst + 2359296, gid - 294912, 96, 768);
    else                   wconv_one(s3, dst + 4128768, gid - 516096, 96, 768);
}

__global__ __launch_bounds__(256) void wconv_ff(const float* __restrict__ f1,
                                                const float* __restrict__ f2,
                                                __bf16* __restrict__ dst) {
    const int gid = blockIdx.x * 256 + threadIdx.x;   // < 393216
    if (gid < 196608) wconv_one(f1, dst,           gid,          96, 768);
    else              wconv_one(f2, dst + 1572864, gid - 196608, 256, 2048);
}

// ---------------------------------------------------------------------------
// GEMM: Y[M=4096][ldy] = Xb[M][K] * Wb[N][K]^T + bias. Tile 128 x BN, BK=64.
// Both operands pre-swizzled bf16 in global; staged via global_load_lds(16B).
// OUT: 0 = fp32 Yf, 1 = swizzled bf16 Yb, 2 = final NCHW transpose into Yf.
// ---------------------------------------------------------------------------
template <int RELU, int OUT, int BN>
__global__ __launch_bounds__(256) void gemm_bt(const __bf16* __restrict__ Xb,
                                               const __bf16* __restrict__ Wb,
                                               const float* __restrict__ bias,
                                               float* __restrict__ Yf,
                                               __bf16* __restrict__ Yb,
                                               int ldy, int K) {
    __shared__ __bf16 As[128 * 64];
    __shared__ __bf16 Bs[BN * 64];

    const int tid = threadIdx.x;
    const int lane = tid & 63;
    const int wave = tid >> 6;
    constexpr int NI = (BN == 128) ? 4 : 2;
    const int wr = (BN == 128) ? (wave >> 1) : wave;
    const int wc = (BN == 128) ? (wave & 1) : 0;
    const int lr = lane & 15;

    // XCD-aware bijective block swizzle (all grids have nwg % 8 == 0)
    const int nx = gridDim.x;
    int bid = blockIdx.y * nx + blockIdx.x;
    const int cpx = (nx * gridDim.y) >> 3;
    bid = (bid & 7) * cpx + (bid >> 3);
    const int by = bid / nx;
    const int bx = bid - by * nx;
    const int mBase = by * 128;
    const int nBase = bx * BN;

    const int brow = lane >> 3;
    const __bf16* Ap = Xb + (size_t)mBase * K + ((lane & 7) << 3);
    const __bf16* Bp = Wb + (size_t)nBase * K + ((lane & 7) << 3);

    f32x4 acc[NI][4];
#pragma unroll
    for (int i = 0; i < NI; ++i)
#pragma unroll
        for (int j = 0; j < 4; ++j) {
            f32x4 z = {0.f, 0.f, 0.f, 0.f};
            acc[i][j] = z;
        }

    for (int kt = 0; kt < K; kt += 64) {
#pragma unroll
        for (int i = 0; i < 4; ++i) {
            const int r0 = (wave << 5) + (i << 3);
            gload_lds16(Ap + (size_t)(r0 + brow) * K + kt, &As[r0 << 6]);
        }
#pragma unroll
        for (int i = 0; i < BN / 32; ++i) {
            const int r0 = wave * (BN / 4) + (i << 3);
            gload_lds16(Bp + (size_t)(r0 + brow) * K + kt, &Bs[r0 << 6]);
        }
        __syncthreads();
#pragma unroll
        for (int kk = 0; kk < 2; ++kk) {
            const int q = (lane >> 4) + (kk << 2);
            bf16x8 af[NI], bfv[4];
#pragma unroll
            for (int i = 0; i < NI; ++i) {
                const int r = wr * (NI * 16) + i * 16 + lr;
                af[i] = *(const bf16x8*)&As[(r << 6) + ((q ^ (r & 7)) << 3)];
            }
#pragma unroll
            for (int j = 0; j < 4; ++j) {
                const int r = wc * 64 + j * 16 + lr;
                bfv[j] = *(const bf16x8*)&Bs[(r << 6) + ((q ^ (r & 7)) << 3)];
            }
#pragma unroll
            for (int i = 0; i < NI; ++i)
#pragma unroll
                for (int j = 0; j < 4; ++j)
                    acc[i][j] = __builtin_amdgcn_mfma_f32_16x16x32_bf16(af[i], bfv[j], acc[i][j], 0, 0, 0);
        }
        __syncthreads();
    }

    const int rsub = (lane >> 4) << 2;
#pragma unroll
    for (int i = 0; i < NI; ++i)
#pragma unroll
        for (int j = 0; j < 4; ++j) {
            const int col = nBase + wc * 64 + j * 16 + lr;
            const float bv = bias[col];
#pragma unroll
            for (int rr = 0; rr < 4; ++rr) {
                const int row = mBase + wr * (NI * 16) + i * 16 + rsub + rr;
                float v = acc[i][j][rr] + bv;
                if (RELU) v = fmaxf(v, 0.f);
                if (OUT == 1) {
                    Yb[(size_t)row * ldy + swzcol(col, row)] = (__bf16)v;
                } else if (OUT == 2) {
                    const int b_ = row >> 8, s_ = row & 255;
                    const int w_ = col / 3, c_ = col - w_ * 3;
                    Yf[(size_t)b_ * 196608 + (size_t)c_ * 65536 + s_ * 256 + w_] = v;
                } else {
                    Yf[(size_t)row * ldy + col] = v;
                }
            }
        }
}

// ---------------------------------------------------------------------------
// MFMA flash attention, swizzled-QKV aware. Grid (192 bh, 4 q-blocks of 64).
// ---------------------------------------------------------------------------
__global__ __launch_bounds__(256) void attn_mfma(const __bf16* __restrict__ QKV,
                                                 __bf16* __restrict__ Oout,
                                                 int causal) {
    const int bh = blockIdx.x;
    const int qq = blockIdx.y;
    const int b = bh / 12, h = bh - b * 12;
    const int tid = threadIdx.x;
    const int lane = tid & 63;
    const int w = tid >> 6;
    const int g = lane >> 4;
    const int c = lane & 15;
    const int c7 = c & 7;

    __shared__ __bf16 Ks[64 * 64];   // content swizzled per row (linear copy of global)
    __shared__ __bf16 Vs[64 * 66];   // true layout, stride 66

    const int q64 = (w << 4) + c;
    const int qrow = (qq << 6) + q64;
    // Q row stored swizzled; true granule t at position t^(qrow&7), qrow&7 == c7
    const __bf16* qp = QKV + (size_t)((b << 8) + qrow) * 2304 + (h << 6);
    bf16x8 qf0 = *(const bf16x8*)(qp + ((g ^ c7) << 3));
    bf16x8 qf1 = *(const bf16x8*)(qp + (((g + 4) ^ c7) << 3));

    f32x4 oacc[4];
#pragma unroll
    for (int i = 0; i < 4; ++i) { f32x4 z = {0.f, 0.f, 0.f, 0.f}; oacc[i] = z; }
    float mrun = -1e30f, lrun = 0.f;

    const int nt = causal ? (qq + 1) : 4;
    const int sr = tid >> 2;
    const int sg0 = (tid & 3) << 1;
    const int sp = sg0 << 3;

    for (int kt = 0; kt < nt; ++kt) {
        __syncthreads();
        // K tile: linear global_load_lds copy (content already per-row swizzled)
        {
            const __bf16* Kp = QKV + (size_t)((b << 8) + (kt << 6)) * 2304 + 768 + (h << 6) + ((lane & 7) << 3);
#pragma unroll
            for (int i = 0; i < 2; ++i) {
                const int r0 = (w << 4) + (i << 3);
                gload_lds16(Kp + (size_t)(r0 + (lane >> 3)) * 2304, &Ks[r0 << 6]);
            }
        }
        // V tile: load swizzled positions, store to TRUE positions (stride 66)
        {
            const __bf16* vp = QKV + (size_t)((b << 8) + (kt << 6) + sr) * 2304 + 1536 + (h << 6);
            bf16x8 v0 = *(const bf16x8*)(vp + sp);        // true granule sg0^s7
            bf16x8 v1 = *(const bf16x8*)(vp + sp + 8);    // true granule (sg0+1)^s7
            const int s7 = sr & 7;
            uint32_t* d0 = (uint32_t*)&Vs[sr * 66 + ((sg0 ^ s7) << 3)];
            uint32_t* d1 = (uint32_t*)&Vs[sr * 66 + (((sg0 + 1) ^ s7) << 3)];
            const uint32_t* u0 = (const uint32_t*)&v0;
            const uint32_t* u1 = (const uint32_t*)&v1;
            d0[0] = u0[0]; d0[1] = u0[1]; d0[2] = u0[2]; d0[3] = u0[3];
            d1[0] = u1[0]; d1[1] = u1[1]; d1[2] = u1[2]; d1[3] = u1[3];
        }
        __syncthreads();

        // ---- QK^T (swapped): S^T frags, rows k, col q ----
        f32x4 sc[4];
#pragma unroll
        for (int mf = 0; mf < 4; ++mf) { f32x4 z = {0.f, 0.f, 0.f, 0.f}; sc[mf] = z; }
#pragma unroll
        for (int mf = 0; mf < 4; ++mf) {
            const int row = (mf << 4) + c;
            bf16x8 af0 = *(const bf16x8*)&Ks[(row << 6) + ((g ^ c7) << 3)];
            sc[mf] = __builtin_amdgcn_mfma_f32_16x16x32_bf16(af0, qf0, sc[mf], 0, 0, 0);
            bf16x8 af1 = *(const bf16x8*)&Ks[(row << 6) + (((g + 4) ^ c7) << 3)];
            sc[mf] = __builtin_amdgcn_mfma_f32_16x16x32_bf16(af1, qf1, sc[mf], 0, 0, 0);
        }

        const int diag = (causal && kt == qq);
        float tm = -1e30f;
#pragma unroll
        for (int mf = 0; mf < 4; ++mf)
#pragma unroll
            for (int r = 0; r < 4; ++r) {
                float v = sc[mf][r] * 0.125f;
                if (diag && ((mf << 4) + (g << 2) + r > q64)) v = -1e30f;
                sc[mf][r] = v;
                tm = fmaxf(tm, v);
            }
        tm = fmaxf(tm, __shfl_xor(tm, 16));
        tm = fmaxf(tm, __shfl_xor(tm, 32));
        const float mnew = fmaxf(mrun, tm);
        const float rs = __expf(mrun - mnew);
        mrun = mnew;
        lrun *= rs;
#pragma unroll
        for (int i = 0; i < 4; ++i) {
            oacc[i][0] *= rs; oacc[i][1] *= rs; oacc[i][2] *= rs; oacc[i][3] *= rs;
        }

        // ---- P = exp(S - m) -> swizzled Ps (reuse of per-wave private band) ----
        __shared__ __bf16 Ps[64 * 64];
#pragma unroll
        for (int mf = 0; mf < 4; ++mf) {
            const int kg = (mf << 1) + (g >> 1);
            const int e = (g & 1) << 2;
#pragma unroll
            for (int r = 0; r < 4; ++r) {
                float p = __expf(sc[mf][r] - mnew);
                lrun += p;
                Ps[(q64 << 6) + ((kg ^ c7) << 3) + e + r] = (__bf16)p;
            }
        }

        // ---- PV: O^T[d][q] += V^T x P ----
#pragma unroll
        for (int kc = 0; kc < 2; ++kc) {
            bf16x8 pb = *(const bf16x8*)&Ps[(q64 << 6) + (((g + (kc << 2)) ^ c7) << 3)];
#pragma unroll
            for (int df = 0; df < 4; ++df) {
                bf16x8 av;
#pragma unroll
                for (int j = 0; j < 8; ++j)
                    av[j] = Vs[((g << 3) + j + (kc << 5)) * 66 + (df << 4) + c];
                oacc[df] = __builtin_amdgcn_mfma_f32_16x16x32_bf16(av, pb, oacc[df], 0, 0, 0);
            }
        }
    }

    // ---- epilogue: write swizzled bf16 (row key = qrow&7 = c7) ----
    lrun += __shfl_xor(lrun, 16);
    lrun += __shfl_xor(lrun, 32);
    const float inv = 1.f / lrun;
    __bf16* op = Oout + (size_t)((b << 8) + qrow) * 768 + (h << 6);
#pragma unroll
    for (int df = 0; df < 4; ++df) {
        bf16x4 ov;
        ov[0] = (__bf16)(oacc[df][0] * inv);
        ov[1] = (__bf16)(oacc[df][1] * inv);
        ov[2] = (__bf16)(oacc[df][2] * inv);
        ov[3] = (__bf16)(oacc[df][3] * inv);
        const int gran = (df << 1) + (g >> 1);
        *(bf16x4*)(op + ((gran ^ c7) << 3) + ((g & 1) << 2)) = ov;
    }
}

// ---------------------------------------------------------------------------
// Fused residual + LayerNorm; writes fp32 x and swizzled bf16 xb.
// ---------------------------------------------------------------------------
__global__ __launch_bounds__(256) void resid_ln(float* __restrict__ x,
                                                __bf16* __restrict__ xb,
                                                const float* __restrict__ r,
                                                const float* __restrict__ g,
                                                const float* __restrict__ b) {
    const int row = blockIdx.x, tid = threadIdx.x;
    float* xp = x + (size_t)row * 768;
    __bf16* xbp = xb + (size_t)row * 768;
    const float* rp = r + (size_t)row * 768;

    float v0 = xp[tid] + rp[tid];
    float v1 = xp[tid + 256] + rp[tid + 256];
    float v2 = xp[tid + 512] + rp[tid + 512];

    __shared__ float red[4];
    float s = v0 + v1 + v2;
#pragma unroll
    for (int off = 32; off > 0; off >>= 1) s += __shfl_down(s, off, 64);
    if ((tid & 63) == 0) red[tid >> 6] = s;
    __syncthreads();
    const float mean = (red[0] + red[1] + red[2] + red[3]) * (1.0f / 768.0f);
    __syncthreads();

    float d0 = v0 - mean, d1 = v1 - mean, d2 = v2 - mean;
    float q = d0 * d0 + d1 * d1 + d2 * d2;
#pragma unroll
    for (int off = 32; off > 0; off >>= 1) q += __shfl_down(q, off, 64);
    if ((tid & 63) == 0) red[tid >> 6] = q;
    __syncthreads();
    const float inv = rsqrtf((red[0] + red[1] + red[2] + red[3]) * (1.0f / 768.0f) + 1e-5f);

    const float o0 = d0 * inv * g[tid] + b[tid];
    const float o1 = d1 * inv * g[tid + 256] + b[tid + 256];
    const float o2 = d2 * inv * g[tid + 512] + b[tid + 512];
    xp[tid] = o0;       xbp[swzcol(tid, row)] = (__bf16)o0;
    xp[tid + 256] = o1; xbp[swzcol(tid + 256, row)] = (__bf16)o1;
    xp[tid + 512] = o2; xbp[swzcol(tid + 512, row)] = (__bf16)o2;
}

// x = enc + PE (fp32), xb = swz bf16(x), encb = swz bf16(enc). 8 elems/thread.
__global__ __launch_bounds__(256) void add_pe(const float* __restrict__ e,
                                              float* __restrict__ x,
                                              __bf16* __restrict__ xb,
                                              __bf16* __restrict__ encb) {
    const int gid = blockIdx.x * 256 + threadIdx.x;   // granule id, < 393216
    const int m = gid / 96;
    const int g8 = gid - m * 96;
    const int col0 = g8 << 3;
    const int s = m & 255;

    float4 e0 = *(const float4*)(e + (size_t)m * 768 + col0);
    float4 e1 = *(const float4*)(e + (size_t)m * 768 + col0 + 4);

    float pe[8];
#pragma unroll
    for (int p = 0; p < 4; ++p) {
        const int d = col0 + 2 * p;
        const float div = __expf((float)d * (-0.011992630693328381f));
        const float ang = (float)s * div;
        pe[2 * p] = __sinf(ang);
        pe[2 * p + 1] = __cosf(ang);
    }
    float4 v0, v1;
    v0.x = e0.x + pe[0]; v0.y = e0.y + pe[1]; v0.z = e0.z + pe[2]; v0.w = e0.w + pe[3];
    v1.x = e1.x + pe[4]; v1.y = e1.y + pe[5]; v1.z = e1.z + pe[6]; v1.w = e1.w + pe[7];

    *(float4*)(x + (size_t)m * 768 + col0) = v0;
    *(float4*)(x + (size_t)m * 768 + col0 + 4) = v1;

    const int scb = (col0 & ~63) | ((((g8 & 7) ^ (m & 7)) << 3));
    *(bf16x8*)&xb[(size_t)m * 768 + scb] = cvt8(v0, v1);
    *(bf16x8*)&encb[(size_t)m * 768 + scb] = cvt8(e0, e1);
}

// ---------------------------------------------------------------------------
extern "C" void kernel_launch(void* const* d_in, const int* in_sizes, int n_in,
                              void* d_out, int out_size, void* d_ws, size_t ws_size,
                              hipStream_t stream) {
    const float* enc         = (const float*)d_in[0];
    const float* W_self_in   = (const float*)d_in[1];
    const float* b_self_in   = (const float*)d_in[2];
    const float* W_self_out  = (const float*)d_in[3];
    const float* b_self_out  = (const float*)d_in[4];
    const float* W_cross_in  = (const float*)d_in[5];
    const float* b_cross_in  = (const float*)d_in[6];
    const float* W_cross_out = (const float*)d_in[7];
    const float* b_cross_out = (const float*)d_in[8];
    const float* ln1_g       = (const float*)d_in[9];
    const float* ln1_b       = (const float*)d_in[10];
    const float* ln2_g       = (const float*)d_in[11];
    const float* ln2_b       = (const float*)d_in[12];
    const float* ln3_g       = (const float*)d_in[13];
    const float* ln3_b       = (const float*)d_in[14];
    const float* W_ff1       = (const float*)d_in[15];
    const float* b_ff1       = (const float*)d_in[16];
    const float* W_ff2       = (const float*)d_in[17];
    const float* b_ff2       = (const float*)d_in[18];
    const float* W_patch     = (const float*)d_in[19];
    const float* b_patch     = (const float*)d_in[20];

    float* out = (float*)d_out;
    float* ws  = (float*)d_ws;

    // workspace (float offsets), total 18,087,936 f = 72.4 MB
    float*  x       = ws;                                  // 3,145,728 f
    __bf16* xb      = (__bf16*)(ws + 3145728);             // 3,145,728 bf
    __bf16* qkvb    = (__bf16*)(ws + 4718592);             // 9,437,184 bf (also FFN buf)
    __bf16* attnout = (__bf16*)(ws + 9437184);             // 3,145,728 bf
    float*  proj    = ws + 11010048;                       // 3,145,728 f
    __bf16* encb    = (__bf16*)(ws + 14155776);            // 3,145,728 bf
    __bf16* wbuf    = (__bf16*)(ws + 15728640);            // 4,718,592 bf

    add_pe<<<1536, 256, 0, stream>>>(enc, x, xb, encb);

    for (int l = 0; l < 6; ++l) {
        const float* Wsi = W_self_in   + (size_t)l * 2304 * 768;
        const float* Wso = W_self_out  + (size_t)l * 768 * 768;
        const float* Wci = W_cross_in  + (size_t)l * 2304 * 768;
        const float* Wco = W_cross_out + (size_t)l * 768 * 768;
        const float* Wf1 = W_ff1       + (size_t)l * 2048 * 768;
        const float* Wf2 = W_ff2       + (size_t)l * 768 * 2048;

        wconv4<<<2304, 256, 0, stream>>>(Wsi, Wso, Wci, Wco, wbuf);

        // ---- self attention ----
        gemm_bt<0, 1, 128><<<dim3(18, 32), 256, 0, stream>>>(xb, wbuf, b_self_in + l * 2304,
                                                             nullptr, qkvb, 2304, 768);
        attn_mfma<<<dim3(192, 4), 256, 0, stream>>>(qkvb, attnout, 1);
        gemm_bt<0, 0, 64><<<dim3(12, 32), 256, 0, stream>>>(attnout, wbuf + 1769472,
                                                            b_self_out + l * 768,
                                                            proj, nullptr, 768, 768);
        resid_ln<<<4096, 256, 0, stream>>>(x, xb, proj, ln1_g + l * 768, ln1_b + l * 768);

        // ---- cross attention ----
        gemm_bt<0, 1, 64><<<dim3(12, 32), 256, 0, stream>>>(xb, wbuf + 2359296,
                                                            b_cross_in + l * 2304,
                                                            nullptr, qkvb, 2304, 768);
        gemm_bt<0, 1, 128><<<dim3(12, 32), 256, 0, stream>>>(encb, wbuf + 2949120,
                                                             b_cross_in + l * 2304 + 768,
                                                             nullptr, qkvb + 768, 2304, 768);
        attn_mfma<<<dim3(192, 4), 256, 0, stream>>>(qkvb, attnout, 0);
        gemm_bt<0, 0, 64><<<dim3(12, 32), 256, 0, stream>>>(attnout, wbuf + 4128768,
                                                            b_cross_out + l * 768,
                                                            proj, nullptr, 768, 768);
        resid_ln<<<4096, 256, 0, stream>>>(x, xb, proj, ln2_g + l * 768, ln2_b + l * 768);

        // ---- FFN ----
        wconv_ff<<<1536, 256, 0, stream>>>(Wf1, Wf2, wbuf);
        gemm_bt<1, 1, 128><<<dim3(16, 32), 256, 0, stream>>>(xb, wbuf, b_ff1 + l * 2048,
                                                             nullptr, qkvb, 2048, 768);
        gemm_bt<0, 0, 64><<<dim3(12, 32), 256, 0, stream>>>(qkvb, wbuf + 1572864,
                                                            b_ff2 + l * 768,
                                                            proj, nullptr, 768, 2048);
        resid_ln<<<4096, 256, 0, stream>>>(x, xb, proj, ln3_g + l * 768, ln3_b + l * 768);
    }

    // ---- final projection fused with NCHW transpose ----
    wconv<<<288, 256, 0, stream>>>(W_patch, wbuf);
    gemm_bt<0, 2, 64><<<dim3(12, 32), 256, 0, stream>>>(xb, wbuf, b_patch,
                                                        out, nullptr, 768, 768);
}

// Round 5
// 1352.414 us; speedup vs baseline: 3.3874x; 1.0722x over previous
//
#include <hip/hip_runtime.h>
#include <hip/hip_bf16.h>

#define DEV __device__ __forceinline__
#define WAITVM(N) asm volatile("s_waitcnt vmcnt(" #N ")" ::: "memory")

typedef __bf16 bf16x8 __attribute__((ext_vector_type(8)));
typedef __bf16 bf16x4 __attribute__((ext_vector_type(4)));
typedef float  f32x4  __attribute__((ext_vector_type(4)));

DEV bf16x8 cvt8(const float4 a, const float4 b) {
    bf16x8 r;
    r[0] = (__bf16)a.x; r[1] = (__bf16)a.y; r[2] = (__bf16)a.z; r[3] = (__bf16)a.w;
    r[4] = (__bf16)b.x; r[5] = (__bf16)b.y; r[6] = (__bf16)b.z; r[7] = (__bf16)b.w;
    return r;
}

DEV void gload_lds16(const __bf16* g, __bf16* l) {
    __builtin_amdgcn_global_load_lds(
        (const __attribute__((address_space(1))) void*)g,
        (__attribute__((address_space(3))) void*)l, 16, 0, 0);
}

// swizzled column: within each 64-elem chunk, granule g stores source g^(row&7)
DEV int swzcol(int col, int row) {
    return (col & ~63) | ((((col >> 3) & 7) ^ (row & 7)) << 3) | (col & 7);
}

// ---------------------------------------------------------------------------
// Weight converts: fp32 [N][K] -> bf16 [N][K], granule-swizzled.
// ---------------------------------------------------------------------------
DEV void wconv_one(const float* __restrict__ src, __bf16* __restrict__ dst,
                   int lg, int gpr, int K) {
    const int n = lg / gpr;
    const int gi = lg - n * gpr;
    const int cb = (gi >> 3) << 6;
    const int g = gi & 7;
    const float* sp = src + (size_t)n * K + cb + ((g ^ (n & 7)) << 3);
    float4 a = *(const float4*)sp;
    float4 b = *(const float4*)(sp + 4);
    *(bf16x8*)&dst[(size_t)lg * 8] = cvt8(a, b);
}

__global__ __launch_bounds__(256) void wconv(const float* __restrict__ W,
                                             __bf16* __restrict__ Wb) {
    const int gid = blockIdx.x * 256 + threadIdx.x;
    wconv_one(W, Wb, gid, 96, 768);
}

__global__ __launch_bounds__(256) void wconv4(const float* __restrict__ s0,
                                              const float* __restrict__ s1,
                                              const float* __restrict__ s2,
                                              const float* __restrict__ s3,
                                              __bf16* __restrict__ dst) {
    const int gid = blockIdx.x * 256 + threadIdx.x;   // < 589824
    if (gid < 221184)      wconv_one(s0, dst,           gid,          96, 768);
    else if (gid < 294912) wconv_one(s1, dst + 1769472, gid - 221184, 96, 768);
    else if (gid < 516096) wconv_one(s2, dst + 2359296, gid - 294912, 96, 768);
    else                   wconv_one(s3, dst + 4128768, gid - 516096, 96, 768);
}

__global__ __launch_bounds__(256) void wconv_ff(const float* __restrict__ f1,
                                                const float* __restrict__ f2,
                                                __bf16* __restrict__ dst) {
    const int gid = blockIdx.x * 256 + threadIdx.x;   // < 393216
    if (gid < 196608) wconv_one(f1, dst,           gid,          96, 768);
    else              wconv_one(f2, dst + 1572864, gid - 196608, 256, 2048);
}

// ---------------------------------------------------------------------------
// GEMM: Y[M=4096][ldy] = Xb[M][K] * Wb[N][K]^T + bias. Tile 128 x BN, BK=64.
// 2-phase double-buffered pipeline: counted vmcnt + raw s_barrier (T3+T4).
// OUT: 1 = swizzled bf16, 2 = NCHW fp32 final transpose, 3 = linear bf16.
// ---------------------------------------------------------------------------
template <int RELU, int OUT, int BN>
__global__ __launch_bounds__(256) void gemm_bt(const __bf16* __restrict__ Xb,
                                               const __bf16* __restrict__ Wb,
                                               const float* __restrict__ bias,
                                               float* __restrict__ Yf,
                                               __bf16* __restrict__ Yb,
                                               int ldy, int K) {
    constexpr int ABUF = 128 * 64;
    constexpr int BBUF = BN * 64;
    __shared__ __bf16 As[2 * ABUF];
    __shared__ __bf16 Bs[2 * BBUF];

    const int tid = threadIdx.x;
    const int lane = tid & 63;
    const int wave = tid >> 6;
    constexpr int NI = (BN == 128) ? 4 : 2;
    const int wr = (BN == 128) ? (wave >> 1) : wave;
    const int wc = (BN == 128) ? (wave & 1) : 0;
    const int lr = lane & 15;

    // XCD-aware bijective block swizzle (all grids have nwg % 8 == 0)
    const int nx = gridDim.x;
    int bid = blockIdx.y * nx + blockIdx.x;
    const int cpx = (nx * gridDim.y) >> 3;
    bid = (bid & 7) * cpx + (bid >> 3);
    const int by = bid / nx;
    const int bx = bid - by * nx;
    const int mBase = by * 128;
    const int nBase = bx * BN;

    const int brow = lane >> 3;
    const __bf16* Ap = Xb + (size_t)mBase * K + ((lane & 7) << 3);
    const __bf16* Bp = Wb + (size_t)nBase * K + ((lane & 7) << 3);

    f32x4 acc[NI][4];
#pragma unroll
    for (int i = 0; i < NI; ++i)
#pragma unroll
        for (int j = 0; j < 4; ++j) {
            f32x4 z = {0.f, 0.f, 0.f, 0.f};
            acc[i][j] = z;
        }

    auto STAGE = [&](int sel, int kt) {
#pragma unroll
        for (int i = 0; i < 4; ++i) {
            const int r0 = (wave << 5) + (i << 3);
            gload_lds16(Ap + (size_t)(r0 + brow) * K + kt, &As[sel * ABUF + (r0 << 6)]);
        }
#pragma unroll
        for (int i = 0; i < BN / 32; ++i) {
            const int r0 = wave * (BN / 4) + (i << 3);
            gload_lds16(Bp + (size_t)(r0 + brow) * K + kt, &Bs[sel * BBUF + (r0 << 6)]);
        }
    };

    auto COMPUTE = [&](int sel) {
#pragma unroll
        for (int kk = 0; kk < 2; ++kk) {
            const int q = (lane >> 4) + (kk << 2);
            bf16x8 af[NI], bfv[4];
#pragma unroll
            for (int i = 0; i < NI; ++i) {
                const int r = wr * (NI * 16) + i * 16 + lr;
                af[i] = *(const bf16x8*)&As[sel * ABUF + (r << 6) + ((q ^ (r & 7)) << 3)];
            }
#pragma unroll
            for (int j = 0; j < 4; ++j) {
                const int r = wc * 64 + j * 16 + lr;
                bfv[j] = *(const bf16x8*)&Bs[sel * BBUF + (r << 6) + ((q ^ (r & 7)) << 3)];
            }
#pragma unroll
            for (int i = 0; i < NI; ++i)
#pragma unroll
                for (int j = 0; j < 4; ++j)
                    acc[i][j] = __builtin_amdgcn_mfma_f32_16x16x32_bf16(af[i], bfv[j], acc[i][j], 0, 0, 0);
        }
    };

    // ---- 2-phase pipeline: prefetch next tile during compute of current ----
    STAGE(0, 0);
    int sel = 0;
    for (int kt = 0; kt + 64 < K; kt += 64) {
        STAGE(sel ^ 1, kt + 64);
        if constexpr (BN == 128) WAITVM(8); else WAITVM(6);
        __builtin_amdgcn_s_barrier();              // current tile fully in LDS
        __builtin_amdgcn_sched_barrier(0);
        COMPUTE(sel);
        __builtin_amdgcn_sched_barrier(0);
        __builtin_amdgcn_s_barrier();              // all reads done before overwrite
        sel ^= 1;
    }
    WAITVM(0);
    __builtin_amdgcn_s_barrier();
    __builtin_amdgcn_sched_barrier(0);
    COMPUTE(sel);

    // ---- epilogue ----
    const int rsub = (lane >> 4) << 2;
#pragma unroll
    for (int i = 0; i < NI; ++i)
#pragma unroll
        for (int j = 0; j < 4; ++j) {
            const int col = nBase + wc * 64 + j * 16 + lr;
            const float bv = bias[col];
#pragma unroll
            for (int rr = 0; rr < 4; ++rr) {
                const int row = mBase + wr * (NI * 16) + i * 16 + rsub + rr;
                float v = acc[i][j][rr] + bv;
                if (RELU) v = fmaxf(v, 0.f);
                if (OUT == 1) {
                    Yb[(size_t)row * ldy + swzcol(col, row)] = (__bf16)v;
                } else if (OUT == 2) {
                    const int b_ = row >> 8, s_ = row & 255;
                    const int w_ = col / 3, c_ = col - w_ * 3;
                    Yf[(size_t)b_ * 196608 + (size_t)c_ * 65536 + s_ * 256 + w_] = v;
                } else {
                    Yb[(size_t)row * ldy + col] = (__bf16)v;   // OUT==3 linear bf16
                }
            }
        }
}

// ---------------------------------------------------------------------------
// MFMA flash attention, swizzled-QKV aware. Grid (192 bh, 4 q-blocks of 64).
// ---------------------------------------------------------------------------
__global__ __launch_bounds__(256) void attn_mfma(const __bf16* __restrict__ QKV,
                                                 __bf16* __restrict__ Oout,
                                                 int causal) {
    const int bh = blockIdx.x;
    const int qq = blockIdx.y;
    const int b = bh / 12, h = bh - b * 12;
    const int tid = threadIdx.x;
    const int lane = tid & 63;
    const int w = tid >> 6;
    const int g = lane >> 4;
    const int c = lane & 15;
    const int c7 = c & 7;

    __shared__ __bf16 Ks[64 * 64];
    __shared__ __bf16 Vs[64 * 66];

    const int q64 = (w << 4) + c;
    const int qrow = (qq << 6) + q64;
    const __bf16* qp = QKV + (size_t)((b << 8) + qrow) * 2304 + (h << 6);
    bf16x8 qf0 = *(const bf16x8*)(qp + ((g ^ c7) << 3));
    bf16x8 qf1 = *(const bf16x8*)(qp + (((g + 4) ^ c7) << 3));

    f32x4 oacc[4];
#pragma unroll
    for (int i = 0; i < 4; ++i) { f32x4 z = {0.f, 0.f, 0.f, 0.f}; oacc[i] = z; }
    float mrun = -1e30f, lrun = 0.f;

    const int nt = causal ? (qq + 1) : 4;
    const int sr = tid >> 2;
    const int sg0 = (tid & 3) << 1;
    const int sp = sg0 << 3;

    for (int kt = 0; kt < nt; ++kt) {
        __syncthreads();
        {
            const __bf16* Kp = QKV + (size_t)((b << 8) + (kt << 6)) * 2304 + 768 + (h << 6) + ((lane & 7) << 3);
#pragma unroll
            for (int i = 0; i < 2; ++i) {
                const int r0 = (w << 4) + (i << 3);
                gload_lds16(Kp + (size_t)(r0 + (lane >> 3)) * 2304, &Ks[r0 << 6]);
            }
        }
        {
            const __bf16* vp = QKV + (size_t)((b << 8) + (kt << 6) + sr) * 2304 + 1536 + (h << 6);
            bf16x8 v0 = *(const bf16x8*)(vp + sp);
            bf16x8 v1 = *(const bf16x8*)(vp + sp + 8);
            const int s7 = sr & 7;
            uint32_t* d0 = (uint32_t*)&Vs[sr * 66 + ((sg0 ^ s7) << 3)];
            uint32_t* d1 = (uint32_t*)&Vs[sr * 66 + (((sg0 + 1) ^ s7) << 3)];
            const uint32_t* u0 = (const uint32_t*)&v0;
            const uint32_t* u1 = (const uint32_t*)&v1;
            d0[0] = u0[0]; d0[1] = u0[1]; d0[2] = u0[2]; d0[3] = u0[3];
            d1[0] = u1[0]; d1[1] = u1[1]; d1[2] = u1[2]; d1[3] = u1[3];
        }
        __syncthreads();

        f32x4 sc[4];
#pragma unroll
        for (int mf = 0; mf < 4; ++mf) { f32x4 z = {0.f, 0.f, 0.f, 0.f}; sc[mf] = z; }
#pragma unroll
        for (int mf = 0; mf < 4; ++mf) {
            const int row = (mf << 4) + c;
            bf16x8 af0 = *(const bf16x8*)&Ks[(row << 6) + ((g ^ c7) << 3)];
            sc[mf] = __builtin_amdgcn_mfma_f32_16x16x32_bf16(af0, qf0, sc[mf], 0, 0, 0);
            bf16x8 af1 = *(const bf16x8*)&Ks[(row << 6) + (((g + 4) ^ c7) << 3)];
            sc[mf] = __builtin_amdgcn_mfma_f32_16x16x32_bf16(af1, qf1, sc[mf], 0, 0, 0);
        }

        const int diag = (causal && kt == qq);
        float tm = -1e30f;
#pragma unroll
        for (int mf = 0; mf < 4; ++mf)
#pragma unroll
            for (int r = 0; r < 4; ++r) {
                float v = sc[mf][r] * 0.125f;
                if (diag && ((mf << 4) + (g << 2) + r > q64)) v = -1e30f;
                sc[mf][r] = v;
                tm = fmaxf(tm, v);
            }
        tm = fmaxf(tm, __shfl_xor(tm, 16));
        tm = fmaxf(tm, __shfl_xor(tm, 32));
        const float mnew = fmaxf(mrun, tm);
        const float rs = __expf(mrun - mnew);
        mrun = mnew;
        lrun *= rs;
#pragma unroll
        for (int i = 0; i < 4; ++i) {
            oacc[i][0] *= rs; oacc[i][1] *= rs; oacc[i][2] *= rs; oacc[i][3] *= rs;
        }

        __shared__ __bf16 Ps[64 * 64];
#pragma unroll
        for (int mf = 0; mf < 4; ++mf) {
            const int kg = (mf << 1) + (g >> 1);
            const int e = (g & 1) << 2;
#pragma unroll
            for (int r = 0; r < 4; ++r) {
                float p = __expf(sc[mf][r] - mnew);
                lrun += p;
                Ps[(q64 << 6) + ((kg ^ c7) << 3) + e + r] = (__bf16)p;
            }
        }

#pragma unroll
        for (int kc = 0; kc < 2; ++kc) {
            bf16x8 pb = *(const bf16x8*)&Ps[(q64 << 6) + (((g + (kc << 2)) ^ c7) << 3)];
#pragma unroll
            for (int df = 0; df < 4; ++df) {
                bf16x8 av;
#pragma unroll
                for (int j = 0; j < 8; ++j)
                    av[j] = Vs[((g << 3) + j + (kc << 5)) * 66 + (df << 4) + c];
                oacc[df] = __builtin_amdgcn_mfma_f32_16x16x32_bf16(av, pb, oacc[df], 0, 0, 0);
            }
        }
    }

    lrun += __shfl_xor(lrun, 16);
    lrun += __shfl_xor(lrun, 32);
    const float inv = 1.f / lrun;
    __bf16* op = Oout + (size_t)((b << 8) + qrow) * 768 + (h << 6);
#pragma unroll
    for (int df = 0; df < 4; ++df) {
        bf16x4 ov;
        ov[0] = (__bf16)(oacc[df][0] * inv);
        ov[1] = (__bf16)(oacc[df][1] * inv);
        ov[2] = (__bf16)(oacc[df][2] * inv);
        ov[3] = (__bf16)(oacc[df][3] * inv);
        const int gran = (df << 1) + (g >> 1);
        *(bf16x4*)(op + ((gran ^ c7) << 3) + ((g & 1) << 2)) = ov;
    }
}

// ---------------------------------------------------------------------------
// Fused residual + LayerNorm; reads bf16 proj, writes fp32 x + swizzled bf16 xb.
// ---------------------------------------------------------------------------
__global__ __launch_bounds__(256) void resid_ln(float* __restrict__ x,
                                                __bf16* __restrict__ xb,
                                                const __bf16* __restrict__ r,
                                                const float* __restrict__ g,
                                                const float* __restrict__ b) {
    const int row = blockIdx.x, tid = threadIdx.x;
    float* xp = x + (size_t)row * 768;
    __bf16* xbp = xb + (size_t)row * 768;
    const __bf16* rp = r + (size_t)row * 768;

    float v0 = xp[tid] + (float)rp[tid];
    float v1 = xp[tid + 256] + (float)rp[tid + 256];
    float v2 = xp[tid + 512] + (float)rp[tid + 512];

    __shared__ float red[4];
    float s = v0 + v1 + v2;
#pragma unroll
    for (int off = 32; off > 0; off >>= 1) s += __shfl_down(s, off, 64);
    if ((tid & 63) == 0) red[tid >> 6] = s;
    __syncthreads();
    const float mean = (red[0] + red[1] + red[2] + red[3]) * (1.0f / 768.0f);
    __syncthreads();

    float d0 = v0 - mean, d1 = v1 - mean, d2 = v2 - mean;
    float q = d0 * d0 + d1 * d1 + d2 * d2;
#pragma unroll
    for (int off = 32; off > 0; off >>= 1) q += __shfl_down(q, off, 64);
    if ((tid & 63) == 0) red[tid >> 6] = q;
    __syncthreads();
    const float inv = rsqrtf((red[0] + red[1] + red[2] + red[3]) * (1.0f / 768.0f) + 1e-5f);

    const float o0 = d0 * inv * g[tid] + b[tid];
    const float o1 = d1 * inv * g[tid + 256] + b[tid + 256];
    const float o2 = d2 * inv * g[tid + 512] + b[tid + 512];
    xp[tid] = o0;       xbp[swzcol(tid, row)] = (__bf16)o0;
    xp[tid + 256] = o1; xbp[swzcol(tid + 256, row)] = (__bf16)o1;
    xp[tid + 512] = o2; xbp[swzcol(tid + 512, row)] = (__bf16)o2;
}

// x = enc + PE (fp32), xb = swz bf16(x), encb = swz bf16(enc). 8 elems/thread.
__global__ __launch_bounds__(256) void add_pe(const float* __restrict__ e,
                                              float* __restrict__ x,
                                              __bf16* __restrict__ xb,
                                              __bf16* __restrict__ encb) {
    const int gid = blockIdx.x * 256 + threadIdx.x;   // granule id, < 393216
    const int m = gid / 96;
    const int g8 = gid - m * 96;
    const int col0 = g8 << 3;
    const int s = m & 255;

    float4 e0 = *(const float4*)(e + (size_t)m * 768 + col0);
    float4 e1 = *(const float4*)(e + (size_t)m * 768 + col0 + 4);

    float pe[8];
#pragma unroll
    for (int p = 0; p < 4; ++p) {
        const int d = col0 + 2 * p;
        const float div = __expf((float)d * (-0.011992630693328381f));
        const float ang = (float)s * div;
        pe[2 * p] = __sinf(ang);
        pe[2 * p + 1] = __cosf(ang);
    }
    float4 v0, v1;
    v0.x = e0.x + pe[0]; v0.y = e0.y + pe[1]; v0.z = e0.z + pe[2]; v0.w = e0.w + pe[3];
    v1.x = e1.x + pe[4]; v1.y = e1.y + pe[5]; v1.z = e1.z + pe[6]; v1.w = e1.w + pe[7];

    *(float4*)(x + (size_t)m * 768 + col0) = v0;
    *(float4*)(x + (size_t)m * 768 + col0 + 4) = v1;

    const int scb = (col0 & ~63) | ((((g8 & 7) ^ (m & 7)) << 3));
    *(bf16x8*)&xb[(size_t)m * 768 + scb] = cvt8(v0, v1);
    *(bf16x8*)&encb[(size_t)m * 768 + scb] = cvt8(e0, e1);
}

// ---------------------------------------------------------------------------
extern "C" void kernel_launch(void* const* d_in, const int* in_sizes, int n_in,
                              void* d_out, int out_size, void* d_ws, size_t ws_size,
                              hipStream_t stream) {
    const float* enc         = (const float*)d_in[0];
    const float* W_self_in   = (const float*)d_in[1];
    const float* b_self_in   = (const float*)d_in[2];
    const float* W_self_out  = (const float*)d_in[3];
    const float* b_self_out  = (const float*)d_in[4];
    const float* W_cross_in  = (const float*)d_in[5];
    const float* b_cross_in  = (const float*)d_in[6];
    const float* W_cross_out = (const float*)d_in[7];
    const float* b_cross_out = (const float*)d_in[8];
    const float* ln1_g       = (const float*)d_in[9];
    const float* ln1_b       = (const float*)d_in[10];
    const float* ln2_g       = (const float*)d_in[11];
    const float* ln2_b       = (const float*)d_in[12];
    const float* ln3_g       = (const float*)d_in[13];
    const float* ln3_b       = (const float*)d_in[14];
    const float* W_ff1       = (const float*)d_in[15];
    const float* b_ff1       = (const float*)d_in[16];
    const float* W_ff2       = (const float*)d_in[17];
    const float* b_ff2       = (const float*)d_in[18];
    const float* W_patch     = (const float*)d_in[19];
    const float* b_patch     = (const float*)d_in[20];

    float* out = (float*)d_out;
    float* ws  = (float*)d_ws;

    float*  x       = ws;                                  // 3,145,728 f
    __bf16* xb      = (__bf16*)(ws + 3145728);             // 3,145,728 bf
    __bf16* qkvb    = (__bf16*)(ws + 4718592);             // 9,437,184 bf (also FFN buf)
    __bf16* attnout = (__bf16*)(ws + 9437184);             // 3,145,728 bf
    __bf16* projb   = (__bf16*)(ws + 11010048);            // 3,145,728 bf
    __bf16* encb    = (__bf16*)(ws + 14155776);            // 3,145,728 bf
    __bf16* wbuf    = (__bf16*)(ws + 15728640);            // 4,718,592 bf

    add_pe<<<1536, 256, 0, stream>>>(enc, x, xb, encb);

    for (int l = 0; l < 6; ++l) {
        const float* Wsi = W_self_in   + (size_t)l * 2304 * 768;
        const float* Wso = W_self_out  + (size_t)l * 768 * 768;
        const float* Wci = W_cross_in  + (size_t)l * 2304 * 768;
        const float* Wco = W_cross_out + (size_t)l * 768 * 768;
        const float* Wf1 = W_ff1       + (size_t)l * 2048 * 768;
        const float* Wf2 = W_ff2       + (size_t)l * 768 * 2048;

        wconv4<<<2304, 256, 0, stream>>>(Wsi, Wso, Wci, Wco, wbuf);

        // ---- self attention ----
        gemm_bt<0, 1, 128><<<dim3(18, 32), 256, 0, stream>>>(xb, wbuf, b_self_in + l * 2304,
                                                             nullptr, qkvb, 2304, 768);
        attn_mfma<<<dim3(192, 4), 256, 0, stream>>>(qkvb, attnout, 1);
        gemm_bt<0, 3, 64><<<dim3(12, 32), 256, 0, stream>>>(attnout, wbuf + 1769472,
                                                            b_self_out + l * 768,
                                                            nullptr, projb, 768, 768);
        resid_ln<<<4096, 256, 0, stream>>>(x, xb, projb, ln1_g + l * 768, ln1_b + l * 768);

        // ---- cross attention ----
        gemm_bt<0, 1, 64><<<dim3(12, 32), 256, 0, stream>>>(xb, wbuf + 2359296,
                                                            b_cross_in + l * 2304,
                                                            nullptr, qkvb, 2304, 768);
        gemm_bt<0, 1, 128><<<dim3(12, 32), 256, 0, stream>>>(encb, wbuf + 2949120,
                                                             b_cross_in + l * 2304 + 768,
                                                             nullptr, qkvb + 768, 2304, 768);
        attn_mfma<<<dim3(192, 4), 256, 0, stream>>>(qkvb, attnout, 0);
        gemm_bt<0, 3, 64><<<dim3(12, 32), 256, 0, stream>>>(attnout, wbuf + 4128768,
                                                            b_cross_out + l * 768,
                                                            nullptr, projb, 768, 768);
        resid_ln<<<4096, 256, 0, stream>>>(x, xb, projb, ln2_g + l * 768, ln2_b + l * 768);

        // ---- FFN ----
        wconv_ff<<<1536, 256, 0, stream>>>(Wf1, Wf2, wbuf);
        gemm_bt<1, 1, 128><<<dim3(16, 32), 256, 0, stream>>>(xb, wbuf, b_ff1 + l * 2048,
                                                             nullptr, qkvb, 2048, 768);
        gemm_bt<0, 3, 64><<<dim3(12, 32), 256, 0, stream>>>(qkvb, wbuf + 1572864,
                                                            b_ff2 + l * 768,
                                                            nullptr, projb, 768, 2048);
        resid_ln<<<4096, 256, 0, stream>>>(x, xb, projb, ln3_g + l * 768, ln3_b + l * 768);
    }

    // ---- final projection fused with NCHW transpose ----
    wconv<<<288, 256, 0, stream>>>(W_patch, wbuf);
    gemm_bt<0, 2, 64><<<dim3(12, 32), 256, 0, stream>>>(xb, wbuf, b_patch,
                                                        out, nullptr, 768, 768);
}